// Round 14
// baseline (220.121 us; speedup 1.0000x reference)
//
#include <hip/hip_runtime.h>

// WCSA: B=2, N=4096, Cc=C=512, Cs=128, H=8, dc=d=64, ds=16.
// Internal compute: bf16 MFMA + fp32 accumulation. I/O dtype runtime-detected
// (fp32 confirmed; bf16 path kept).
//
// Head layout: reshape(B,N,C)->(B,H,N,d) direct => head h of a projection is
// the contiguous 512-row slab, row-major (4096,d).
//
// R21: one-time fp32->bf16 conversion pass. proj's fp32 path (R19: FETCH
// 85.6MB vs 43 compulsory, 16 loads + 64 cvt/K-step, latency-bound at 24%
// HBM) pays the 2x-byte + cvt tax on EVERY A-panel re-read. cvt_inputs
// streams activations+weights to bf16 once (~64MB traffic ~10us):
//  - activations (18.9MB) -> d_out as scratch (legal: chan_av cols 0-511 +
//    flash cols 512-639 overwrite every output byte after proj is done);
//  - weights (2.65MB) -> qk-scratch region, time-shared (weights live
//    during proj; chan_qk partials overwrite after) -- same WIDE+8MB gate
//    R20 proved passes.
// proj<1> = single bf16 path (picks orig vs converted ptrs per flag);
// proj<0> = legacy dual path for the non-gated case (= R20 behavior).
// Numerics identical (same RTN cast, hoisted). flash = control (~67.3us).

typedef __attribute__((ext_vector_type(8))) __bf16 bf16x8;
typedef __attribute__((ext_vector_type(4))) __bf16 bf16x4;
typedef __attribute__((ext_vector_type(4))) float  f32x4;
typedef __attribute__((ext_vector_type(4))) short  s16x4;

#define LOG2E 1.44269504088896340736f

// 16x16x16 bf16 MFMA: A/B = 4 bf16 (2 VGPRs), C/D = 4 f32.
static __device__ __forceinline__ f32x4 mfma16(bf16x4 a, bf16x4 b, f32x4 c)
{
#if __has_builtin(__builtin_amdgcn_mfma_f32_16x16x16bf16_1k)
    union { bf16x4 h; s16x4 s; } ua, ub;
    ua.h = a; ub.h = b;
    return __builtin_amdgcn_mfma_f32_16x16x16bf16_1k(ua.s, ub.s, c, 0, 0, 0);
#elif __has_builtin(__builtin_amdgcn_mfma_f32_16x16x16_bf16)
    return __builtin_amdgcn_mfma_f32_16x16x16_bf16(a, b, c, 0, 0, 0);
#else
    asm("v_mfma_f32_16x16x16_bf16 %0, %1, %2, %0" : "+v"(c) : "v"(a), "v"(b));
    return c;
#endif
}

// ---------------------------------------------------------------------------
__global__ void detect_dtype(const unsigned* __restrict__ temp, int* __restrict__ flag)
{
    if (threadIdx.x == 0) {
        const unsigned w = temp[0];
        flag[0] = ((w >> 16) == (w & 0xffffu)) ? 1 : 0;  // 1 = bf16 I/O
    }
}

// ---------------------------------------------------------------------------
// One-time fp32 -> bf16 conversion of all 9 proj operands (3 activations +
// 6 weights). Early-exits when I/O is already bf16. Grid-stride over f32x4
// chunks; segment lookup via prefix table (<=9 steps).
// ---------------------------------------------------------------------------
struct CvtArgs {
    const float* src[9];
    __bf16*      dst[9];
    int          ofs[10];  // prefix sums, units of f32x4 chunks
};

__global__ __launch_bounds__(256) void cvt_inputs(CvtArgs a, const int* __restrict__ flag)
{
    if (*flag) return;  // bf16 I/O: nothing to convert
    const int total = a.ofs[9];
    for (int c = blockIdx.x * 256 + threadIdx.x; c < total; c += gridDim.x * 256) {
        int g = 0;
        while (c >= a.ofs[g + 1]) ++g;
        const int off = c - a.ofs[g];
        const f32x4 v = ((const f32x4*)a.src[g])[off];
        bf16x4 w;
#pragma unroll
        for (int e = 0; e < 4; ++e) w[e] = (__bf16)v[e];
        ((bf16x4*)a.dst[g])[off] = w;
    }
}

// ---------------------------------------------------------------------------
// Fused projection GEMMs, 128(M)x128(N) tile, BK=64, register prefetch.
// 4 waves in 2(M)x2(N); wave tile 64x64 = 4x4 of 16x16x32 MFMA (32 MFMA/iter).
// blockIdx.y -> group via prefix table in units of 128-wide N-tiles.
// CVT=1: single bf16 path (orig ptrs if bf16 I/O, converted otherwise).
// CVT=0: legacy dual path (fp32 inputs staged with cvt-at-store).
// LDS row stride 72 bf16.
// ---------------------------------------------------------------------------
struct ProjArgs {
    const void*   X[6];
    const void*   W[6];
    const __bf16* Xc[6];
    const __bf16* Wc[6];
    __bf16*       Y[6];
    int           K[6];
    int           yofs[7];  // units of 128-wide N tiles
    int           ng;
};

template <int CVT>
__global__ __launch_bounds__(256) void proj_gemm(ProjArgs args,
                                                 const int* __restrict__ flag)
{
    __shared__ __align__(16) __bf16 As[128][72];
    __shared__ __align__(16) __bf16 Bs[128][72];
    const int bf = *flag;
    const int by = blockIdx.y;
    int g = 0;
    while (by >= args.yofs[g + 1]) ++g;  // <=6 iters, wave-uniform
    const int n0 = (by - args.yofs[g]) * 128;
    const int N  = (args.yofs[g + 1] - args.yofs[g]) * 128;
    const int K  = args.K[g];

    const int m0 = blockIdx.x * 128;
    const int t = threadIdx.x;
    const int wave = t >> 6, lane = t & 63;
    const int wr = (wave >> 1) * 64, wc = (wave & 1) * 64;
    const int m16 = lane & 15, quad = lane >> 4;

    f32x4 acc[4][4];
#pragma unroll
    for (int i = 0; i < 4; ++i)
#pragma unroll
        for (int j = 0; j < 4; ++j) acc[i][j] = (f32x4){0.f, 0.f, 0.f, 0.f};

    if (CVT || bf) {
        // ---- bf16 operands (native or pre-converted): A 4x + B 4x bf16x8 --
        const __bf16* Xb = (CVT && !bf) ? args.Xc[g] : (const __bf16*)args.X[g];
        const __bf16* Wb = (CVT && !bf) ? args.Wc[g] : (const __bf16*)args.W[g];
        bf16x8 pa[4], pb[4];
        auto load = [&](int k0) {
#pragma unroll
            for (int i = 0; i < 4; ++i) {
                const int idx = t + i * 256, row = idx >> 3, off = (idx & 7) * 8;
                pa[i] = *(const bf16x8*)(Xb + (size_t)(m0 + row) * K + k0 + off);
            }
#pragma unroll
            for (int i = 0; i < 4; ++i) {
                const int idx = t + i * 256, row = idx >> 3, off = (idx & 7) * 8;
                pb[i] = *(const bf16x8*)(Wb + (size_t)(n0 + row) * K + k0 + off);
            }
        };
        load(0);
        for (int k0 = 0; k0 < K; k0 += 64) {
            __syncthreads();
#pragma unroll
            for (int i = 0; i < 4; ++i) {
                const int idx = t + i * 256, row = idx >> 3, off = (idx & 7) * 8;
                *(bf16x8*)&As[row][off] = pa[i];
            }
#pragma unroll
            for (int i = 0; i < 4; ++i) {
                const int idx = t + i * 256, row = idx >> 3, off = (idx & 7) * 8;
                *(bf16x8*)&Bs[row][off] = pb[i];
            }
            __syncthreads();
            if (k0 + 64 < K) load(k0 + 64);
#pragma unroll
            for (int kc = 0; kc < 2; ++kc) {
                const int ko = kc * 32 + quad * 8;
                bf16x8 a[4], b[4];
#pragma unroll
                for (int i = 0; i < 4; ++i) a[i] = *(const bf16x8*)&As[wr + i * 16 + m16][ko];
#pragma unroll
                for (int j = 0; j < 4; ++j) b[j] = *(const bf16x8*)&Bs[wc + j * 16 + m16][ko];
#pragma unroll
                for (int i = 0; i < 4; ++i)
#pragma unroll
                    for (int j = 0; j < 4; ++j)
                        acc[i][j] = __builtin_amdgcn_mfma_f32_16x16x32_bf16(a[i], b[j], acc[i][j], 0, 0, 0);
            }
        }
    } else {
        // ---- legacy fp32 path (only when CVT=0): A 8x + B 8x f32x4 -------
        const float* Xf = (const float*)args.X[g];
        const float* Wf = (const float*)args.W[g];
        f32x4 pa[8], pb[8];
        auto load = [&](int k0) {
#pragma unroll
            for (int i = 0; i < 8; ++i) {
                const int idx = t + i * 256, row = idx >> 4, c = (idx & 15) * 4;
                pa[i] = *(const f32x4*)(Xf + (size_t)(m0 + row) * K + k0 + c);
            }
#pragma unroll
            for (int i = 0; i < 8; ++i) {
                const int idx = t + i * 256, row = idx >> 4, c = (idx & 15) * 4;
                pb[i] = *(const f32x4*)(Wf + (size_t)(n0 + row) * K + k0 + c);
            }
        };
        load(0);
        for (int k0 = 0; k0 < K; k0 += 64) {
            __syncthreads();
#pragma unroll
            for (int i = 0; i < 8; ++i) {
                const int idx = t + i * 256, row = idx >> 4, c = (idx & 15) * 4;
                bf16x4 ha;
#pragma unroll
                for (int e = 0; e < 4; ++e) ha[e] = (__bf16)pa[i][e];
                *(bf16x4*)&As[row][c] = ha;
            }
#pragma unroll
            for (int i = 0; i < 8; ++i) {
                const int idx = t + i * 256, row = idx >> 4, c = (idx & 15) * 4;
                bf16x4 hb;
#pragma unroll
                for (int e = 0; e < 4; ++e) hb[e] = (__bf16)pb[i][e];
                *(bf16x4*)&Bs[row][c] = hb;
            }
            __syncthreads();
            if (k0 + 64 < K) load(k0 + 64);
#pragma unroll
            for (int kc = 0; kc < 2; ++kc) {
                const int ko = kc * 32 + quad * 8;
                bf16x8 a[4], b[4];
#pragma unroll
                for (int i = 0; i < 4; ++i) a[i] = *(const bf16x8*)&As[wr + i * 16 + m16][ko];
#pragma unroll
                for (int j = 0; j < 4; ++j) b[j] = *(const bf16x8*)&Bs[wc + j * 16 + m16][ko];
#pragma unroll
                for (int i = 0; i < 4; ++i)
#pragma unroll
                    for (int j = 0; j < 4; ++j)
                        acc[i][j] = __builtin_amdgcn_mfma_f32_16x16x32_bf16(a[i], b[j], acc[i][j], 0, 0, 0);
            }
        }
    }
    __bf16* Y = args.Y[g];
#pragma unroll
    for (int i = 0; i < 4; ++i)
#pragma unroll
        for (int j = 0; j < 4; ++j)
#pragma unroll
            for (int r = 0; r < 4; ++r) {
                const int gm = m0 + wr + i * 16 + quad * 4 + r;
                const int gn = n0 + wc + j * 16 + m16;
                Y[(size_t)gm * N + gn] = (__bf16)acc[i][j][r];
            }
}

// ---------------------------------------------------------------------------
__global__ __launch_bounds__(256) void zero_f32(float* __restrict__ p, int n)
{
    const int i = blockIdx.x * 256 + threadIdx.x;
    if (i < n) p[i] = 0.f;
}

// ---------------------------------------------------------------------------
// Channel QK v3 (MFMA): S[bh][i][j] = sum_n Qc[n][i]*Kc[n][j], 32 n-splits
// of 128. Stage Q^T/K^T in LDS (coalesced loads + transpose scatter).
// ATOMIC=1: atomics into S (legacy). ATOMIC=0: plain stores into
// Spart[bx][64][64]; chan_softmax<32> consumes splits directly.
// ---------------------------------------------------------------------------
template <int ATOMIC>
__global__ __launch_bounds__(256) void chan_qk(const __bf16* __restrict__ Qc,
                                               const __bf16* __restrict__ Kc,
                                               float* __restrict__ S)
{
    __shared__ __align__(16) __bf16 Qt[64][136];  // [channel][token] (Q^T)
    __shared__ __align__(16) __bf16 Kt[64][136];
    const int bx = blockIdx.x;
    const int bh = bx >> 5, split = bx & 31;
    const int b = bh >> 3, hh = bh & 7;
    const int n0 = split * 128;
    const int t = threadIdx.x;
    const size_t base = ((size_t)b * 4096 + (size_t)hh * 512) * 512;

    for (int idx = t; idx < 1024; idx += 256) {
        const int row = idx >> 3, c0 = (idx & 7) * 8;  // token row, channel base
        bf16x8 q = *(const bf16x8*)(Qc + base + (size_t)(n0 + row) * 64 + c0);
        bf16x8 k = *(const bf16x8*)(Kc + base + (size_t)(n0 + row) * 64 + c0);
#pragma unroll
        for (int e = 0; e < 8; ++e) {
            Qt[c0 + e][row] = q[e];
            Kt[c0 + e][row] = k[e];
        }
    }
    __syncthreads();

    const int wave = t >> 6, lane = t & 63;
    const int m16 = lane & 15, quad = lane >> 4;

    f32x4 acc[4];
#pragma unroll
    for (int tj = 0; tj < 4; ++tj) acc[tj] = (f32x4){0.f, 0.f, 0.f, 0.f};

#pragma unroll
    for (int ks = 0; ks < 4; ++ks) {
        const int ko = ks * 32 + quad * 8;
        bf16x8 af = *(const bf16x8*)&Qt[wave * 16 + m16][ko];
#pragma unroll
        for (int tj = 0; tj < 4; ++tj) {
            bf16x8 bfr = *(const bf16x8*)&Kt[tj * 16 + m16][ko];
            acc[tj] = __builtin_amdgcn_mfma_f32_16x16x32_bf16(af, bfr, acc[tj], 0, 0, 0);
        }
    }

    if (ATOMIC) {
        float* Sb = S + (size_t)bh * 4096;
#pragma unroll
        for (int tj = 0; tj < 4; ++tj)
#pragma unroll
            for (int r = 0; r < 4; ++r)
                atomicAdd(&Sb[(wave * 16 + quad * 4 + r) * 64 + tj * 16 + m16], acc[tj][r]);
    } else {
        float* Sp = S + (size_t)bx * 4096;
#pragma unroll
        for (int tj = 0; tj < 4; ++tj)
#pragma unroll
            for (int r = 0; r < 4; ++r)
                Sp[(wave * 16 + quad * 4 + r) * 64 + tj * 16 + m16] = acc[tj][r];
    }
}

// ---------------------------------------------------------------------------
// Channel softmax v2: one WAVE per 64-elem row; shfl_xor max/sum.
// NSPLIT>1: fuses the qk split reduction (reads 32 partial tiles).
// ---------------------------------------------------------------------------
template <int NSPLIT>
__global__ __launch_bounds__(256) void chan_softmax(const float* __restrict__ S,
                                                    const void* __restrict__ temp,
                                                    __bf16* __restrict__ P,
                                                    const int* __restrict__ flag)
{
    const int row = blockIdx.x * 4 + (threadIdx.x >> 6);  // 0..1023
    const int bh = row >> 6, i = row & 63;
    const int hh = bh & 7;
    const int j = threadIdx.x & 63;
    const float tv = (*flag) ? (float)((const __bf16*)temp)[hh] : ((const float*)temp)[hh];
    const float scale = 0.125f * tv;

    float v;
    if (NSPLIT > 1) {
        const float* p = S + ((size_t)bh * NSPLIT) * 4096 + (size_t)i * 64 + j;
        float s = 0.f;
#pragma unroll
        for (int sp = 0; sp < NSPLIT; ++sp) s += p[(size_t)sp * 4096];
        v = s * scale;
    } else {
        v = S[(size_t)bh * 4096 + (size_t)i * 64 + j] * scale;
    }
    float mx = v;
#pragma unroll
    for (int d = 1; d < 64; d <<= 1) mx = fmaxf(mx, __shfl_xor(mx, d, 64));
    const float e = __builtin_amdgcn_exp2f((v - mx) * LOG2E);
    float sum = e;
#pragma unroll
    for (int d = 1; d < 64; d <<= 1) sum += __shfl_xor(sum, d, 64);
    P[(size_t)bh * 4096 + (size_t)i * 64 + j] = (__bf16)(e / sum);
}

// ---------------------------------------------------------------------------
// Channel AV v3 (MFMA + LDS-staged operands).
// out[b][h*512 + i*8 + n/512][n%512].
// ---------------------------------------------------------------------------
__global__ __launch_bounds__(256) void chan_av(const __bf16* __restrict__ P,
                                               const __bf16* __restrict__ Vc,
                                               void* __restrict__ out,
                                               const int* __restrict__ flag)
{
    __shared__ __align__(16) __bf16 Pl[64][72];
    __shared__ __align__(16) __bf16 Vl[64][72];
    const int bf = *flag;
    const int bx = blockIdx.x;
    const int bh = bx >> 6, ch = bx & 63;
    const int b = bh >> 3, hh = bh & 7;
    const int n0 = ch * 64;
    const int t = threadIdx.x, wave = t >> 6, lane = t & 63;
    const int m16 = lane & 15, quad = lane >> 4;
    const size_t base = ((size_t)b * 4096 + (size_t)hh * 512) * 512;  // Vc head slab
    const __bf16* Pb = P + (size_t)bh * 4096;

    {
        const int idx0 = t, row0 = idx0 >> 3, off0 = (idx0 & 7) * 8;
        const int idx1 = t + 256, row1 = idx1 >> 3, off1 = (idx1 & 7) * 8;
        *(bf16x8*)&Pl[row0][off0] = *(const bf16x8*)(Pb + (size_t)row0 * 64 + off0);
        *(bf16x8*)&Pl[row1][off1] = *(const bf16x8*)(Pb + (size_t)row1 * 64 + off1);
        *(bf16x8*)&Vl[row0][off0] = *(const bf16x8*)(Vc + base + (size_t)(n0 + row0) * 64 + off0);
        *(bf16x8*)&Vl[row1][off1] = *(const bf16x8*)(Vc + base + (size_t)(n0 + row1) * 64 + off1);
    }
    __syncthreads();

    bf16x8 a[2];
#pragma unroll
    for (int kc = 0; kc < 2; ++kc)
        a[kc] = *(const bf16x8*)&Pl[wave * 16 + m16][kc * 32 + quad * 8];

    f32x4 acc[4];
#pragma unroll
    for (int nt = 0; nt < 4; ++nt) {
        acc[nt] = (f32x4){0.f, 0.f, 0.f, 0.f};
        bf16x8 bv[2];
#pragma unroll
        for (int kc = 0; kc < 2; ++kc)
            bv[kc] = *(const bf16x8*)&Vl[nt * 16 + m16][kc * 32 + quad * 8];
#pragma unroll
        for (int kc = 0; kc < 2; ++kc)
            acc[nt] = __builtin_amdgcn_mfma_f32_16x16x32_bf16(a[kc], bv[kc], acc[nt], 0, 0, 0);
    }

#pragma unroll
    for (int nt = 0; nt < 4; ++nt) {
        const int n = n0 + nt * 16 + m16;
#pragma unroll
        for (int r = 0; r < 4; ++r) {
            const int i = wave * 16 + quad * 4 + r;
            const size_t addr = (size_t)b * 2621440
                              + (size_t)(hh * 512 + i * 8 + (n >> 9)) * 640 + (n & 511);
            if (bf) ((__bf16*)out)[addr] = (__bf16)acc[nt][r];
            else    ((float*)out)[addr]  = acc[nt][r];
        }
    }
}

// ---------------------------------------------------------------------------
// Spatial flash attention v8 (R13-proven form): 512-thread blocks, 8 waves x
// 2 q-groups = 256 q-rows/block; gridDim.y = nsplit key-splits (additive
// combine). Double-buffered K/V LDS (V transposed at stage), one barrier/iter.
// PV in-register via 16x16x16 MFMA; denominator via ones-B MFMA.
// Operand-swap S^T = mfma(K,Q); Q pre-scaled.
// Output: out[b][h*512 + n/8][512 + (n%8)*16 + c].
// ---------------------------------------------------------------------------
template <int PATH>
__global__ __launch_bounds__(512) void flash_sa(const __bf16* __restrict__ Qs,
                                                const __bf16* __restrict__ Ks,
                                                const __bf16* __restrict__ Vs,
                                                const void* __restrict__ temp2,
                                                void* __restrict__ out,
                                                float* __restrict__ po,
                                                float* __restrict__ pl,
                                                const int* __restrict__ flag)
{
    __shared__ __align__(16) __bf16 Kl[2][64][72];
    __shared__ __align__(16) __bf16 Vt[2][16][72];     // V^T: [c][key]
    const int bf = *flag;
    const int bid = blockIdx.x;
    const int qt = bid & 15;            // 256-row q tile
    const int bh = bid >> 4;
    const int b = bh >> 3, hh = bh & 7;
    const int nspl = gridDim.y;
    const int spl  = blockIdx.y;
    const int nkt  = 64 / nspl;
    const int kt0  = spl * nkt;
    const int t = threadIdx.x, wave = t >> 6, lane = t & 63;
    const int m16 = lane & 15, quad = lane >> 4;
    const size_t base  = ((size_t)b * 4096 + (size_t)hh * 512) * 512;
    const size_t vbase = ((size_t)b * 4096 + (size_t)hh * 512) * 128;
    const float tv = bf ? (float)((const __bf16*)temp2)[hh] : ((const float*)temp2)[hh];
    const float sl = 0.125f * tv * LOG2E;

    // Q B-frags for 2 q-groups (lane m16 = qrow, k-contiguous), pre-scaled.
    bf16x8 qa[2][2];
#pragma unroll
    for (int g = 0; g < 2; ++g) {
        const int qrow = qt * 256 + g * 128 + wave * 16 + m16;
#pragma unroll
        for (int kc = 0; kc < 2; ++kc) {
            bf16x8 raw = *(const bf16x8*)(Qs + base + (size_t)qrow * 64 + kc * 32 + quad * 8);
#pragma unroll
            for (int e = 0; e < 8; ++e) qa[g][kc][e] = (__bf16)((float)raw[e] * sl);
        }
    }

    // Ones B-frag for denominator MFMA (row-sum of P).
    bf16x4 ones;
#pragma unroll
    for (int e = 0; e < 4; ++e) ones[e] = (__bf16)1.0f;

    // K/V prefetch registers. K: 512 chunks, 1 per thread. V: threads 0-255.
    const int krow = t >> 3, koff = (t & 7) * 8;
    const bool vact = t < 256;
    const int vrow = t & 63, vcq = (t >> 6) & 3;  // V: b64/thread, c = vcq*4..+4
    bf16x8 pk;
    bf16x4 pv;
    auto pref = [&](int kt) {
        pk = *(const bf16x8*)(Ks + base + (size_t)(kt * 64 + krow) * 64 + koff);
        if (vact) pv = *(const bf16x4*)(Vs + vbase + (size_t)(kt * 64 + vrow) * 16 + vcq * 4);
    };
    auto stage = [&](int bi) {
        *(bf16x8*)&Kl[bi][krow][koff] = pk;
        if (vact) {
#pragma unroll
            for (int e = 0; e < 4; ++e) Vt[bi][vcq * 4 + e][vrow] = pv[e];
        }
    };

    pref(kt0);
    stage(0);
    pref(kt0 + 1);
    __syncthreads();

    f32x4 o[2]  = {(f32x4){0.f, 0.f, 0.f, 0.f}, (f32x4){0.f, 0.f, 0.f, 0.f}};
    f32x4 o2[2] = {(f32x4){0.f, 0.f, 0.f, 0.f}, (f32x4){0.f, 0.f, 0.f, 0.f}};

    for (int kk = 0; kk < nkt; ++kk) {
        const int cur = kk & 1;

        // K/V fragments from current buffer (shared by both q-groups).
        bf16x8 kb[4][2];
        bf16x4 vb16[4];
#pragma unroll
        for (int ct = 0; ct < 4; ++ct)
#pragma unroll
            for (int kc = 0; kc < 2; ++kc)
                kb[ct][kc] = *(const bf16x8*)&Kl[cur][ct * 16 + m16][kc * 32 + quad * 8];
#pragma unroll
        for (int ct = 0; ct < 4; ++ct)
            vb16[ct] = *(const bf16x4*)&Vt[cur][m16][ct * 16 + quad * 4];

        // Stage tile kk+1 into the other buffer; prefetch tile kk+2.
        if (kk + 1 < nkt) stage(cur ^ 1);
        if (kk + 2 < nkt) pref(kt0 + kk + 2);

#pragma unroll
        for (int g = 0; g < 2; ++g) {
            // S^T tiles: D row = key-within-16 (quad*4+r), col = qrow (m16)
            f32x4 st[4];
#pragma unroll
            for (int ct = 0; ct < 4; ++ct) {
                st[ct] = (f32x4){0.f, 0.f, 0.f, 0.f};
#pragma unroll
                for (int kc = 0; kc < 2; ++kc)
                    st[ct] = __builtin_amdgcn_mfma_f32_16x16x32_bf16(kb[ct][kc], qa[g][kc], st[ct], 0, 0, 0);
            }
            // P = exp2(S^T) in-register: lane holds P[qrow=m16][key=ct*16+quad*4+r]
            // == x16-MFMA A-operand layout (row=m16, k=quad*4+e). PV + row-sum.
#pragma unroll
            for (int ct = 0; ct < 4; ++ct) {
                bf16x4 pe;
#pragma unroll
                for (int r = 0; r < 4; ++r)
                    pe[r] = (__bf16)__builtin_amdgcn_exp2f(st[ct][r]);
                o[g]  = mfma16(pe, vb16[ct], o[g]);
                o2[g] = mfma16(pe, ones,     o2[g]);
            }
        }
        __syncthreads();  // next buffer staged; current buffer reads done
    }

    // Guard for the inline-asm MFMA fallback (compiler-unknown latency).
    asm volatile("s_nop 7\n\ts_nop 7");

    if (nspl == 1) {
#pragma unroll
        for (int g = 0; g < 2; ++g) {
#pragma unroll
            for (int r = 0; r < 4; ++r) {
                const int n = qt * 256 + g * 128 + wave * 16 + quad * 4 + r;
                const float val = o[g][r] / o2[g][r];
                const size_t addr = (size_t)b * 2621440
                                  + (size_t)(hh * 512 + (n >> 3)) * 640 + 512 + (n & 7) * 16 + m16;
                if (bf) ((__bf16*)out)[addr] = (__bf16)val;
                else    ((float*)out)[addr]  = val;
            }
        }
    } else {
        // fp32 partials; lane (m16, quad) owns O[n=..+quad*4+r][c=m16].
#pragma unroll
        for (int g = 0; g < 2; ++g) {
#pragma unroll
            for (int r = 0; r < 4; ++r) {
                const int n = qt * 256 + g * 128 + wave * 16 + quad * 4 + r;
                const size_t rowi = ((size_t)spl * 16 + bh) * 4096 + n;
                po[rowi * 16 + m16] = o[g][r];
                if (m16 == 0) pl[rowi] = o2[g][r];  // replicated across cols
            }
        }
    }
}

// ---------------------------------------------------------------------------
// Combine split-K partials: out = (sum_spl po) / (sum_spl pl).
// One thread per (bh, n) row; writes 16 contiguous channels (vectorized).
// ---------------------------------------------------------------------------
__global__ __launch_bounds__(256) void flash_combine(const float* __restrict__ po,
                                                     const float* __restrict__ pl,
                                                     void* __restrict__ out,
                                                     const int* __restrict__ flag,
                                                     int nspl)
{
    const int bf = *flag;
    const int tid = blockIdx.x * 256 + threadIdx.x;  // 65536 rows
    const int bh = tid >> 12, n = tid & 4095;
    const int b = bh >> 3, hh = bh & 7;

    f32x4 acc[4];
#pragma unroll
    for (int q = 0; q < 4; ++q) acc[q] = (f32x4){0.f, 0.f, 0.f, 0.f};
    float l = 0.f;
    for (int sp = 0; sp < nspl; ++sp) {
        const size_t rowi = ((size_t)sp * 16 + bh) * 4096 + n;
        const f32x4* r = (const f32x4*)(po + rowi * 16);
#pragma unroll
        for (int q = 0; q < 4; ++q) {
            const f32x4 v = r[q];
#pragma unroll
            for (int e = 0; e < 4; ++e) acc[q][e] += v[e];
        }
        l += pl[rowi];
    }
    const float inv = 1.f / l;
    const size_t addr = (size_t)b * 2621440
                      + (size_t)(hh * 512 + (n >> 3)) * 640 + 512 + (n & 7) * 16;
    if (bf) {
#pragma unroll
        for (int q = 0; q < 2; ++q) {
            bf16x8 w;
#pragma unroll
            for (int e = 0; e < 8; ++e) w[e] = (__bf16)(acc[q * 2 + (e >> 2)][e & 3] * inv);
            *(bf16x8*)((__bf16*)out + addr + q * 8) = w;
        }
    } else {
#pragma unroll
        for (int q = 0; q < 4; ++q) {
            f32x4 w;
#pragma unroll
            for (int e = 0; e < 4; ++e) w[e] = acc[q][e] * inv;
            *(f32x4*)((float*)out + addr + q * 4) = w;
        }
    }
}

// ---------------------------------------------------------------------------
extern "C" void kernel_launch(void* const* d_in, const int* in_sizes, int n_in,
                              void* d_out, int out_size, void* d_ws, size_t ws_size,
                              hipStream_t stream)
{
    const void* s    = d_in[0];
    const void* h_   = d_in[1];
    const void* sh   = d_in[2];
    const void* t1   = d_in[3];
    const void* t2   = d_in[4];
    const void* Wq_c = d_in[5];
    const void* Wq_s = d_in[6];
    const void* Wk_c = d_in[7];
    const void* Wv_c = d_in[8];
    const void* Wk_s = d_in[9];
    const void* Wv_s = d_in[10];

    const dim3 blk(256);
    const size_t PROJ = 4194304;  // 8192*512 bf16 elements

    const size_t WIDE_BYTES = 5 * PROJ * 2 + 1048576 * 2 + 65536 * 4 + 65536 * 2 + 256;
    const size_t QK_BYTES = 512ull * 4096 * 4;  // 8 MB qk partials / weight-cvt scratch

    if (ws_size >= WIDE_BYTES) {
        // ---------------- wide path (CONFIRMED LIVE, R19 counters) --------
        __bf16* qc = (__bf16*)d_ws;
        __bf16* kc = qc + PROJ;
        __bf16* vc = kc + PROJ;
        __bf16* qs = vc + PROJ;
        __bf16* ks = qs + PROJ;
        __bf16* vs = ks + PROJ;            // 8192x128 row-major
        float*  Sb = (float*)(vs + 1048576);
        __bf16* Pb = (__bf16*)(Sb + 65536);
        int*  flag = (int*)(Pb + 65536);

        detect_dtype<<<dim3(1), dim3(64), 0, stream>>>((const unsigned*)t1, flag);

        const bool extra = (ws_size >= WIDE_BYTES + QK_BYTES);

        ProjArgs pa{};
        const void* Xs[6] = {s, sh, sh, sh, sh, h_};
        const void* Ws[6] = {Wq_c, Wk_c, Wv_c, Wq_s, Wk_s, Wv_s};
        __bf16*     Ys[6] = {qc, kc, vc, qs, ks, vs};
        const int   Ks_[6] = {512, 512, 512, 512, 512, 128};
        const int   yt[6] = {4, 4, 4, 4, 4, 1};  // 128-wide N tiles
        pa.ng = 6;
        int ofs = 0;
        for (int g = 0; g < 6; ++g) {
            pa.X[g] = Xs[g]; pa.W[g] = Ws[g]; pa.Y[g] = Ys[g]; pa.K[g] = Ks_[g];
            pa.yofs[g] = ofs; ofs += yt[g];
        }
        pa.yofs[6] = ofs;  // 21

        if (extra) {
            // bf16 conversion scratch: activations in d_out (fully
            // overwritten by chan_av+flash later); weights in the qk
            // region (consumed by proj, then overwritten by qk partials).
            __bf16* sb  = (__bf16*)d_out;            // 8192x512
            __bf16* shb = sb + PROJ;                 // 8192x512
            __bf16* hb  = shb + PROJ;                // 8192x128
            __bf16* wscr = (__bf16*)((char*)d_ws + WIDE_BYTES);
            __bf16* wcv[6];
            const int wsz[6] = {262144, 262144, 262144, 262144, 262144, 16384};
            int wofs = 0;
            for (int g = 0; g < 6; ++g) { wcv[g] = wscr + wofs; wofs += wsz[g]; }

            CvtArgs ca{};
            const float* csrc[9] = {(const float*)s, (const float*)sh, (const float*)h_,
                                    (const float*)Wq_c, (const float*)Wk_c, (const float*)Wv_c,
                                    (const float*)Wq_s, (const float*)Wk_s, (const float*)Wv_s};
            __bf16* cdst[9] = {sb, shb, hb, wcv[0], wcv[1], wcv[2], wcv[3], wcv[4], wcv[5]};
            const int csz[9] = {1048576, 1048576, 262144,
                                65536, 65536, 65536, 65536, 65536, 4096};  // f32x4 chunks
            int cofs = 0;
            for (int g = 0; g < 9; ++g) {
                ca.src[g] = csrc[g]; ca.dst[g] = cdst[g];
                ca.ofs[g] = cofs; cofs += csz[g];
            }
            ca.ofs[9] = cofs;
            cvt_inputs<<<dim3(2048), blk, 0, stream>>>(ca, flag);

            const __bf16* Xc[6] = {sb, shb, shb, shb, shb, hb};
            for (int g = 0; g < 6; ++g) { pa.Xc[g] = Xc[g]; pa.Wc[g] = wcv[g]; }

            proj_gemm<1><<<dim3(64, 21), blk, 0, stream>>>(pa, flag);

            float* qkscr = (float*)wscr;  // reuse after proj completes
            chan_qk<0><<<dim3(512), blk, 0, stream>>>(qc, kc, qkscr);
            chan_softmax<32><<<dim3(256), blk, 0, stream>>>(qkscr, t1, Pb, flag);
        } else {
            proj_gemm<0><<<dim3(64, 21), blk, 0, stream>>>(pa, flag);
            zero_f32<<<dim3(256), blk, 0, stream>>>(Sb, 65536);
            chan_qk<1><<<dim3(512), blk, 0, stream>>>(qc, kc, Sb);
            chan_softmax<1><<<dim3(256), blk, 0, stream>>>(Sb, t1, Pb, flag);
        }
        chan_av<<<dim3(1024), blk, 0, stream>>>(Pb, vc, d_out, flag);
        // split-K flash: partials live in dead qc/kc/vc region (25 MB,
        // consumed by chan_qk/chan_av which precede flash in-stream).
        float* po = (float*)qc;                  // 4*16*4096*16 f32 = 16.8 MB
        float* pl = po + 4ull * 1048576;         // 4*16*4096 f32
        flash_sa<0><<<dim3(256, 4), dim3(512), 0, stream>>>(qs, ks, vs, t2, d_out, po, pl, flag);
        flash_combine<<<dim3(256), blk, 0, stream>>>(po, pl, d_out, flag, 4);
    } else {
        // ---------------- fallback: sequential reuse (not the live path) --
        __bf16* A  = (__bf16*)d_ws;        // q_c -> v_c -> k_s
        __bf16* Bf = A + PROJ;             // k_c -> q_s
        __bf16* D  = Bf + PROJ;            // v_s: 8192x128 row-major
        float*  Sb = (float*)(D + 1048576);
        __bf16* Pb = (__bf16*)(Sb + 65536);
        int*  flag = (int*)(Pb + 65536);

        detect_dtype<<<dim3(1), dim3(64), 0, stream>>>((const unsigned*)t1, flag);

        auto mk2 = [&](const void* X0, const void* W0, __bf16* Y0, int K0, int t0,
                       const void* X1, const void* W1, __bf16* Y1, int K1, int t1_) {
            ProjArgs p{};
            p.ng = 2;
            p.X[0] = X0; p.W[0] = W0; p.Y[0] = Y0; p.K[0] = K0;
            p.X[1] = X1; p.W[1] = W1; p.Y[1] = Y1; p.K[1] = K1;
            p.yofs[0] = 0; p.yofs[1] = t0; p.yofs[2] = t0 + t1_;
            return p;
        };

        const size_t fb_end = (size_t)((char*)(flag + 1) - (char*)d_ws);
        const size_t pofs = (fb_end + 255) & ~(size_t)255;
        const size_t per_split = (1048576 + 65536) * 4;  // flash po + pl bytes/split
        int nspl = 1;
        if (ws_size >= pofs + 4 * per_split)      nspl = 4;
        else if (ws_size >= pofs + 2 * per_split) nspl = 2;
        const bool qk_part = (ws_size >= pofs + QK_BYTES);
        float* scratch = (float*)((char*)d_ws + pofs);

        ProjArgs p1 = mk2(s,  Wq_c, A,  512, 4, sh, Wk_c, Bf, 512, 4);
        proj_gemm<0><<<dim3(64, 8), blk, 0, stream>>>(p1, flag);
        if (qk_part) {
            chan_qk<0><<<dim3(512), blk, 0, stream>>>(A, Bf, scratch);
            chan_softmax<32><<<dim3(256), blk, 0, stream>>>(scratch, t1, Pb, flag);
        } else {
            zero_f32<<<dim3(256), blk, 0, stream>>>(Sb, 65536);
            chan_qk<1><<<dim3(512), blk, 0, stream>>>(A, Bf, Sb);
            chan_softmax<1><<<dim3(256), blk, 0, stream>>>(Sb, t1, Pb, flag);
        }

        ProjArgs p2 = mk2(sh, Wv_c, A, 512, 4, sh, Wq_s, Bf, 512, 4);
        proj_gemm<0><<<dim3(64, 8), blk, 0, stream>>>(p2, flag);
        chan_av<<<dim3(1024), blk, 0, stream>>>(Pb, A, d_out, flag);

        ProjArgs p3 = mk2(sh, Wk_s, A, 512, 4, h_, Wv_s, D, 128, 1);
        proj_gemm<0><<<dim3(64, 5), blk, 0, stream>>>(p3, flag);

        float* po = scratch;
        float* pl = po + (size_t)nspl * 1048576;
        flash_sa<1><<<dim3(256, nspl), dim3(512), 0, stream>>>(Bf, A, D, t2, d_out, po, pl, flag);
        if (nspl > 1)
            flash_combine<<<dim3(256), blk, 0, stream>>>(po, pl, d_out, flag, nspl);
    }
}

// Round 15
// 215.072 us; speedup vs baseline: 1.0235x; 1.0235x over previous
//
#include <hip/hip_runtime.h>

// WCSA: B=2, N=4096, Cc=C=512, Cs=128, H=8, dc=d=64, ds=16.
// Internal compute: bf16 MFMA + fp32 accumulation. I/O dtype runtime-detected
// (fp32 confirmed; bf16 path kept).
//
// Head layout: reshape(B,N,C)->(B,H,N,d) direct => head h of a projection is
// the contiguous 512-row slab, row-major (4096,d).
//
// R22: (a) R21 cvt REVERTED -- byte ledger was net-negative (+43MB: cvt
// costs 64MB traffic to save 21MB of proj reads; proj at 24% HBM isn't
// BW-ceiling-bound). (b) proj coalesced epilogue: R19 counters show
// WRITE_SIZE 43MB vs 21 ideal + RMW line-fetch in FETCH -- the 64 scalar
// 2B C-stores/thread hit 4x32B half-line segments per instruction (chan_av
// v1's disease). Fix: after K-loop, one barrier, write acc into wave-
// private LDS staging C[wave][64][72] (union-overlays As+Bs, 36864B, no
// growth; wave-private => no 2nd barrier), read back row-contiguous
// bf16x8, store 128B-contiguous segments = full lines. Launcher = R20
// (atomic-free qk chain kept). flash = control (~67.3us).

typedef __attribute__((ext_vector_type(8))) __bf16 bf16x8;
typedef __attribute__((ext_vector_type(4))) __bf16 bf16x4;
typedef __attribute__((ext_vector_type(4))) float  f32x4;
typedef __attribute__((ext_vector_type(4))) short  s16x4;

#define LOG2E 1.44269504088896340736f

// 16x16x16 bf16 MFMA: A/B = 4 bf16 (2 VGPRs), C/D = 4 f32.
static __device__ __forceinline__ f32x4 mfma16(bf16x4 a, bf16x4 b, f32x4 c)
{
#if __has_builtin(__builtin_amdgcn_mfma_f32_16x16x16bf16_1k)
    union { bf16x4 h; s16x4 s; } ua, ub;
    ua.h = a; ub.h = b;
    return __builtin_amdgcn_mfma_f32_16x16x16bf16_1k(ua.s, ub.s, c, 0, 0, 0);
#elif __has_builtin(__builtin_amdgcn_mfma_f32_16x16x16_bf16)
    return __builtin_amdgcn_mfma_f32_16x16x16_bf16(a, b, c, 0, 0, 0);
#else
    asm("v_mfma_f32_16x16x16_bf16 %0, %1, %2, %0" : "+v"(c) : "v"(a), "v"(b));
    return c;
#endif
}

// ---------------------------------------------------------------------------
__global__ void detect_dtype(const unsigned* __restrict__ temp, int* __restrict__ flag)
{
    if (threadIdx.x == 0) {
        const unsigned w = temp[0];
        flag[0] = ((w >> 16) == (w & 0xffffu)) ? 1 : 0;  // 1 = bf16 I/O
    }
}

// ---------------------------------------------------------------------------
// Fused projection GEMMs, 128(M)x128(N) tile, BK=64, register prefetch.
// 4 waves in 2(M)x2(N); wave tile 64x64 = 4x4 of 16x16x32 MFMA (32 MFMA/iter).
// blockIdx.y -> group via prefix table in units of 128-wide N-tiles.
// Coalesced epilogue: acc -> wave-private LDS C[wave][64][72] (overlays
// As/Bs) -> row-contiguous bf16x8 global stores (full 64B lines).
// LDS row stride 72 bf16.
// ---------------------------------------------------------------------------
struct ProjArgs {
    const void* X[6];
    const void* W[6];
    __bf16*     Y[6];
    int         K[6];
    int         yofs[7];  // units of 128-wide N tiles
    int         ng;
};

__global__ __launch_bounds__(256) void proj_gemm(ProjArgs args,
                                                 const int* __restrict__ flag)
{
    __shared__ __align__(16) union ShMem {
        struct { __bf16 A[128][72]; __bf16 B[128][72]; } s;  // 36864 B
        __bf16 C[4][64][72];                                 // 36864 B
    } sm;
    __bf16 (&As)[128][72] = sm.s.A;
    __bf16 (&Bs)[128][72] = sm.s.B;

    const int bf = *flag;
    const int by = blockIdx.y;
    int g = 0;
    while (by >= args.yofs[g + 1]) ++g;  // <=6 iters, wave-uniform
    const int n0 = (by - args.yofs[g]) * 128;
    const int N  = (args.yofs[g + 1] - args.yofs[g]) * 128;
    const int K  = args.K[g];
    const void* X = args.X[g];
    const void* W = args.W[g];
    __bf16*     Y = args.Y[g];

    const int m0 = blockIdx.x * 128;
    const int t = threadIdx.x;
    const int wave = t >> 6, lane = t & 63;
    const int wr = (wave >> 1) * 64, wc = (wave & 1) * 64;
    const int m16 = lane & 15, quad = lane >> 4;

    f32x4 acc[4][4];
#pragma unroll
    for (int i = 0; i < 4; ++i)
#pragma unroll
        for (int j = 0; j < 4; ++j) acc[i][j] = (f32x4){0.f, 0.f, 0.f, 0.f};

    if (bf) {
        // ---- bf16 inputs: prefetch A 4x + B 4x bf16x8 ----
        const __bf16* Xb = (const __bf16*)X;
        const __bf16* Wb = (const __bf16*)W;
        bf16x8 pa[4], pb[4];
        auto load = [&](int k0) {
#pragma unroll
            for (int i = 0; i < 4; ++i) {
                const int idx = t + i * 256, row = idx >> 3, off = (idx & 7) * 8;
                pa[i] = *(const bf16x8*)(Xb + (size_t)(m0 + row) * K + k0 + off);
            }
#pragma unroll
            for (int i = 0; i < 4; ++i) {
                const int idx = t + i * 256, row = idx >> 3, off = (idx & 7) * 8;
                pb[i] = *(const bf16x8*)(Wb + (size_t)(n0 + row) * K + k0 + off);
            }
        };
        load(0);
        for (int k0 = 0; k0 < K; k0 += 64) {
            __syncthreads();
#pragma unroll
            for (int i = 0; i < 4; ++i) {
                const int idx = t + i * 256, row = idx >> 3, off = (idx & 7) * 8;
                *(bf16x8*)&As[row][off] = pa[i];
            }
#pragma unroll
            for (int i = 0; i < 4; ++i) {
                const int idx = t + i * 256, row = idx >> 3, off = (idx & 7) * 8;
                *(bf16x8*)&Bs[row][off] = pb[i];
            }
            __syncthreads();
            if (k0 + 64 < K) load(k0 + 64);
#pragma unroll
            for (int kc = 0; kc < 2; ++kc) {
                const int ko = kc * 32 + quad * 8;
                bf16x8 a[4], b[4];
#pragma unroll
                for (int i = 0; i < 4; ++i) a[i] = *(const bf16x8*)&As[wr + i * 16 + m16][ko];
#pragma unroll
                for (int j = 0; j < 4; ++j) b[j] = *(const bf16x8*)&Bs[wc + j * 16 + m16][ko];
#pragma unroll
                for (int i = 0; i < 4; ++i)
#pragma unroll
                    for (int j = 0; j < 4; ++j)
                        acc[i][j] = __builtin_amdgcn_mfma_f32_16x16x32_bf16(a[i], b[j], acc[i][j], 0, 0, 0);
            }
        }
    } else {
        // ---- fp32 inputs: prefetch A 8x + B 8x f32x4 (cvt at store) ----
        const float* Xf = (const float*)X;
        const float* Wf = (const float*)W;
        f32x4 pa[8], pb[8];
        auto load = [&](int k0) {
#pragma unroll
            for (int i = 0; i < 8; ++i) {
                const int idx = t + i * 256, row = idx >> 4, c = (idx & 15) * 4;
                pa[i] = *(const f32x4*)(Xf + (size_t)(m0 + row) * K + k0 + c);
            }
#pragma unroll
            for (int i = 0; i < 8; ++i) {
                const int idx = t + i * 256, row = idx >> 4, c = (idx & 15) * 4;
                pb[i] = *(const f32x4*)(Wf + (size_t)(n0 + row) * K + k0 + c);
            }
        };
        load(0);
        for (int k0 = 0; k0 < K; k0 += 64) {
            __syncthreads();
#pragma unroll
            for (int i = 0; i < 8; ++i) {
                const int idx = t + i * 256, row = idx >> 4, c = (idx & 15) * 4;
                bf16x4 ha;
#pragma unroll
                for (int e = 0; e < 4; ++e) ha[e] = (__bf16)pa[i][e];
                *(bf16x4*)&As[row][c] = ha;
            }
#pragma unroll
            for (int i = 0; i < 8; ++i) {
                const int idx = t + i * 256, row = idx >> 4, c = (idx & 15) * 4;
                bf16x4 hb;
#pragma unroll
                for (int e = 0; e < 4; ++e) hb[e] = (__bf16)pb[i][e];
                *(bf16x4*)&Bs[row][c] = hb;
            }
            __syncthreads();
            if (k0 + 64 < K) load(k0 + 64);
#pragma unroll
            for (int kc = 0; kc < 2; ++kc) {
                const int ko = kc * 32 + quad * 8;
                bf16x8 a[4], b[4];
#pragma unroll
                for (int i = 0; i < 4; ++i) a[i] = *(const bf16x8*)&As[wr + i * 16 + m16][ko];
#pragma unroll
                for (int j = 0; j < 4; ++j) b[j] = *(const bf16x8*)&Bs[wc + j * 16 + m16][ko];
#pragma unroll
                for (int i = 0; i < 4; ++i)
#pragma unroll
                    for (int j = 0; j < 4; ++j)
                        acc[i][j] = __builtin_amdgcn_mfma_f32_16x16x32_bf16(a[i], b[j], acc[i][j], 0, 0, 0);
            }
        }
    }

    // ---- coalesced epilogue: acc -> LDS (wave-private) -> 128B stores ----
    __syncthreads();  // all waves done reading As/Bs before overlay reuse
#pragma unroll
    for (int i = 0; i < 4; ++i)
#pragma unroll
        for (int j = 0; j < 4; ++j)
#pragma unroll
            for (int r = 0; r < 4; ++r)
                sm.C[wave][i * 16 + quad * 4 + r][j * 16 + m16] = (__bf16)acc[i][j][r];
    // wave-private staging: in-wave LDS dependency, no barrier needed.
#pragma unroll
    for (int p = 0; p < 8; ++p) {
        const int row = p * 8 + (lane >> 3);
        const int c8  = (lane & 7) * 8;
        bf16x8 v = *(const bf16x8*)&sm.C[wave][row][c8];
        *(bf16x8*)&Y[(size_t)(m0 + wr + row) * N + n0 + wc + c8] = v;
    }
}

// ---------------------------------------------------------------------------
__global__ __launch_bounds__(256) void zero_f32(float* __restrict__ p, int n)
{
    const int i = blockIdx.x * 256 + threadIdx.x;
    if (i < n) p[i] = 0.f;
}

// ---------------------------------------------------------------------------
// Channel QK v3 (MFMA): S[bh][i][j] = sum_n Qc[n][i]*Kc[n][j], 32 n-splits
// of 128. Stage Q^T/K^T in LDS (coalesced loads + transpose scatter).
// ATOMIC=1: atomics into S (legacy). ATOMIC=0: plain stores into
// Spart[bx][64][64]; chan_softmax<32> consumes splits directly.
// ---------------------------------------------------------------------------
template <int ATOMIC>
__global__ __launch_bounds__(256) void chan_qk(const __bf16* __restrict__ Qc,
                                               const __bf16* __restrict__ Kc,
                                               float* __restrict__ S)
{
    __shared__ __align__(16) __bf16 Qt[64][136];  // [channel][token] (Q^T)
    __shared__ __align__(16) __bf16 Kt[64][136];
    const int bx = blockIdx.x;
    const int bh = bx >> 5, split = bx & 31;
    const int b = bh >> 3, hh = bh & 7;
    const int n0 = split * 128;
    const int t = threadIdx.x;
    const size_t base = ((size_t)b * 4096 + (size_t)hh * 512) * 512;

    for (int idx = t; idx < 1024; idx += 256) {
        const int row = idx >> 3, c0 = (idx & 7) * 8;  // token row, channel base
        bf16x8 q = *(const bf16x8*)(Qc + base + (size_t)(n0 + row) * 64 + c0);
        bf16x8 k = *(const bf16x8*)(Kc + base + (size_t)(n0 + row) * 64 + c0);
#pragma unroll
        for (int e = 0; e < 8; ++e) {
            Qt[c0 + e][row] = q[e];
            Kt[c0 + e][row] = k[e];
        }
    }
    __syncthreads();

    const int wave = t >> 6, lane = t & 63;
    const int m16 = lane & 15, quad = lane >> 4;

    f32x4 acc[4];
#pragma unroll
    for (int tj = 0; tj < 4; ++tj) acc[tj] = (f32x4){0.f, 0.f, 0.f, 0.f};

#pragma unroll
    for (int ks = 0; ks < 4; ++ks) {
        const int ko = ks * 32 + quad * 8;
        bf16x8 af = *(const bf16x8*)&Qt[wave * 16 + m16][ko];
#pragma unroll
        for (int tj = 0; tj < 4; ++tj) {
            bf16x8 bfr = *(const bf16x8*)&Kt[tj * 16 + m16][ko];
            acc[tj] = __builtin_amdgcn_mfma_f32_16x16x32_bf16(af, bfr, acc[tj], 0, 0, 0);
        }
    }

    if (ATOMIC) {
        float* Sb = S + (size_t)bh * 4096;
#pragma unroll
        for (int tj = 0; tj < 4; ++tj)
#pragma unroll
            for (int r = 0; r < 4; ++r)
                atomicAdd(&Sb[(wave * 16 + quad * 4 + r) * 64 + tj * 16 + m16], acc[tj][r]);
    } else {
        float* Sp = S + (size_t)bx * 4096;
#pragma unroll
        for (int tj = 0; tj < 4; ++tj)
#pragma unroll
            for (int r = 0; r < 4; ++r)
                Sp[(wave * 16 + quad * 4 + r) * 64 + tj * 16 + m16] = acc[tj][r];
    }
}

// ---------------------------------------------------------------------------
// Channel softmax v2: one WAVE per 64-elem row; shfl_xor max/sum.
// NSPLIT>1: fuses the qk split reduction (reads 32 partial tiles).
// ---------------------------------------------------------------------------
template <int NSPLIT>
__global__ __launch_bounds__(256) void chan_softmax(const float* __restrict__ S,
                                                    const void* __restrict__ temp,
                                                    __bf16* __restrict__ P,
                                                    const int* __restrict__ flag)
{
    const int row = blockIdx.x * 4 + (threadIdx.x >> 6);  // 0..1023
    const int bh = row >> 6, i = row & 63;
    const int hh = bh & 7;
    const int j = threadIdx.x & 63;
    const float tv = (*flag) ? (float)((const __bf16*)temp)[hh] : ((const float*)temp)[hh];
    const float scale = 0.125f * tv;

    float v;
    if (NSPLIT > 1) {
        const float* p = S + ((size_t)bh * NSPLIT) * 4096 + (size_t)i * 64 + j;
        float s = 0.f;
#pragma unroll
        for (int sp = 0; sp < NSPLIT; ++sp) s += p[(size_t)sp * 4096];
        v = s * scale;
    } else {
        v = S[(size_t)bh * 4096 + (size_t)i * 64 + j] * scale;
    }
    float mx = v;
#pragma unroll
    for (int d = 1; d < 64; d <<= 1) mx = fmaxf(mx, __shfl_xor(mx, d, 64));
    const float e = __builtin_amdgcn_exp2f((v - mx) * LOG2E);
    float sum = e;
#pragma unroll
    for (int d = 1; d < 64; d <<= 1) sum += __shfl_xor(sum, d, 64);
    P[(size_t)bh * 4096 + (size_t)i * 64 + j] = (__bf16)(e / sum);
}

// ---------------------------------------------------------------------------
// Channel AV v3 (MFMA + LDS-staged operands).
// out[b][h*512 + i*8 + n/512][n%512].
// ---------------------------------------------------------------------------
__global__ __launch_bounds__(256) void chan_av(const __bf16* __restrict__ P,
                                               const __bf16* __restrict__ Vc,
                                               void* __restrict__ out,
                                               const int* __restrict__ flag)
{
    __shared__ __align__(16) __bf16 Pl[64][72];
    __shared__ __align__(16) __bf16 Vl[64][72];
    const int bf = *flag;
    const int bx = blockIdx.x;
    const int bh = bx >> 6, ch = bx & 63;
    const int b = bh >> 3, hh = bh & 7;
    const int n0 = ch * 64;
    const int t = threadIdx.x, wave = t >> 6, lane = t & 63;
    const int m16 = lane & 15, quad = lane >> 4;
    const size_t base = ((size_t)b * 4096 + (size_t)hh * 512) * 512;  // Vc head slab
    const __bf16* Pb = P + (size_t)bh * 4096;

    {
        const int idx0 = t, row0 = idx0 >> 3, off0 = (idx0 & 7) * 8;
        const int idx1 = t + 256, row1 = idx1 >> 3, off1 = (idx1 & 7) * 8;
        *(bf16x8*)&Pl[row0][off0] = *(const bf16x8*)(Pb + (size_t)row0 * 64 + off0);
        *(bf16x8*)&Pl[row1][off1] = *(const bf16x8*)(Pb + (size_t)row1 * 64 + off1);
        *(bf16x8*)&Vl[row0][off0] = *(const bf16x8*)(Vc + base + (size_t)(n0 + row0) * 64 + off0);
        *(bf16x8*)&Vl[row1][off1] = *(const bf16x8*)(Vc + base + (size_t)(n0 + row1) * 64 + off1);
    }
    __syncthreads();

    bf16x8 a[2];
#pragma unroll
    for (int kc = 0; kc < 2; ++kc)
        a[kc] = *(const bf16x8*)&Pl[wave * 16 + m16][kc * 32 + quad * 8];

    f32x4 acc[4];
#pragma unroll
    for (int nt = 0; nt < 4; ++nt) {
        acc[nt] = (f32x4){0.f, 0.f, 0.f, 0.f};
        bf16x8 bv[2];
#pragma unroll
        for (int kc = 0; kc < 2; ++kc)
            bv[kc] = *(const bf16x8*)&Vl[nt * 16 + m16][kc * 32 + quad * 8];
#pragma unroll
        for (int kc = 0; kc < 2; ++kc)
            acc[nt] = __builtin_amdgcn_mfma_f32_16x16x32_bf16(a[kc], bv[kc], acc[nt], 0, 0, 0);
    }

#pragma unroll
    for (int nt = 0; nt < 4; ++nt) {
        const int n = n0 + nt * 16 + m16;
#pragma unroll
        for (int r = 0; r < 4; ++r) {
            const int i = wave * 16 + quad * 4 + r;
            const size_t addr = (size_t)b * 2621440
                              + (size_t)(hh * 512 + i * 8 + (n >> 9)) * 640 + (n & 511);
            if (bf) ((__bf16*)out)[addr] = (__bf16)acc[nt][r];
            else    ((float*)out)[addr]  = acc[nt][r];
        }
    }
}

// ---------------------------------------------------------------------------
// Spatial flash attention v8 (R13-proven form): 512-thread blocks, 8 waves x
// 2 q-groups = 256 q-rows/block; gridDim.y = nsplit key-splits (additive
// combine). Double-buffered K/V LDS (V transposed at stage), one barrier/iter.
// PV in-register via 16x16x16 MFMA; denominator via ones-B MFMA.
// Operand-swap S^T = mfma(K,Q); Q pre-scaled.
// Output: out[b][h*512 + n/8][512 + (n%8)*16 + c].
// ---------------------------------------------------------------------------
template <int PATH>
__global__ __launch_bounds__(512) void flash_sa(const __bf16* __restrict__ Qs,
                                                const __bf16* __restrict__ Ks,
                                                const __bf16* __restrict__ Vs,
                                                const void* __restrict__ temp2,
                                                void* __restrict__ out,
                                                float* __restrict__ po,
                                                float* __restrict__ pl,
                                                const int* __restrict__ flag)
{
    __shared__ __align__(16) __bf16 Kl[2][64][72];
    __shared__ __align__(16) __bf16 Vt[2][16][72];     // V^T: [c][key]
    const int bf = *flag;
    const int bid = blockIdx.x;
    const int qt = bid & 15;            // 256-row q tile
    const int bh = bid >> 4;
    const int b = bh >> 3, hh = bh & 7;
    const int nspl = gridDim.y;
    const int spl  = blockIdx.y;
    const int nkt  = 64 / nspl;
    const int kt0  = spl * nkt;
    const int t = threadIdx.x, wave = t >> 6, lane = t & 63;
    const int m16 = lane & 15, quad = lane >> 4;
    const size_t base  = ((size_t)b * 4096 + (size_t)hh * 512) * 512;
    const size_t vbase = ((size_t)b * 4096 + (size_t)hh * 512) * 128;
    const float tv = bf ? (float)((const __bf16*)temp2)[hh] : ((const float*)temp2)[hh];
    const float sl = 0.125f * tv * LOG2E;

    // Q B-frags for 2 q-groups (lane m16 = qrow, k-contiguous), pre-scaled.
    bf16x8 qa[2][2];
#pragma unroll
    for (int g = 0; g < 2; ++g) {
        const int qrow = qt * 256 + g * 128 + wave * 16 + m16;
#pragma unroll
        for (int kc = 0; kc < 2; ++kc) {
            bf16x8 raw = *(const bf16x8*)(Qs + base + (size_t)qrow * 64 + kc * 32 + quad * 8);
#pragma unroll
            for (int e = 0; e < 8; ++e) qa[g][kc][e] = (__bf16)((float)raw[e] * sl);
        }
    }

    // Ones B-frag for denominator MFMA (row-sum of P).
    bf16x4 ones;
#pragma unroll
    for (int e = 0; e < 4; ++e) ones[e] = (__bf16)1.0f;

    // K/V prefetch registers. K: 512 chunks, 1 per thread. V: threads 0-255.
    const int krow = t >> 3, koff = (t & 7) * 8;
    const bool vact = t < 256;
    const int vrow = t & 63, vcq = (t >> 6) & 3;  // V: b64/thread, c = vcq*4..+4
    bf16x8 pk;
    bf16x4 pv;
    auto pref = [&](int kt) {
        pk = *(const bf16x8*)(Ks + base + (size_t)(kt * 64 + krow) * 64 + koff);
        if (vact) pv = *(const bf16x4*)(Vs + vbase + (size_t)(kt * 64 + vrow) * 16 + vcq * 4);
    };
    auto stage = [&](int bi) {
        *(bf16x8*)&Kl[bi][krow][koff] = pk;
        if (vact) {
#pragma unroll
            for (int e = 0; e < 4; ++e) Vt[bi][vcq * 4 + e][vrow] = pv[e];
        }
    };

    pref(kt0);
    stage(0);
    pref(kt0 + 1);
    __syncthreads();

    f32x4 o[2]  = {(f32x4){0.f, 0.f, 0.f, 0.f}, (f32x4){0.f, 0.f, 0.f, 0.f}};
    f32x4 o2[2] = {(f32x4){0.f, 0.f, 0.f, 0.f}, (f32x4){0.f, 0.f, 0.f, 0.f}};

    for (int kk = 0; kk < nkt; ++kk) {
        const int cur = kk & 1;

        // K/V fragments from current buffer (shared by both q-groups).
        bf16x8 kb[4][2];
        bf16x4 vb16[4];
#pragma unroll
        for (int ct = 0; ct < 4; ++ct)
#pragma unroll
            for (int kc = 0; kc < 2; ++kc)
                kb[ct][kc] = *(const bf16x8*)&Kl[cur][ct * 16 + m16][kc * 32 + quad * 8];
#pragma unroll
        for (int ct = 0; ct < 4; ++ct)
            vb16[ct] = *(const bf16x4*)&Vt[cur][m16][ct * 16 + quad * 4];

        // Stage tile kk+1 into the other buffer; prefetch tile kk+2.
        if (kk + 1 < nkt) stage(cur ^ 1);
        if (kk + 2 < nkt) pref(kt0 + kk + 2);

#pragma unroll
        for (int g = 0; g < 2; ++g) {
            // S^T tiles: D row = key-within-16 (quad*4+r), col = qrow (m16)
            f32x4 st[4];
#pragma unroll
            for (int ct = 0; ct < 4; ++ct) {
                st[ct] = (f32x4){0.f, 0.f, 0.f, 0.f};
#pragma unroll
                for (int kc = 0; kc < 2; ++kc)
                    st[ct] = __builtin_amdgcn_mfma_f32_16x16x32_bf16(kb[ct][kc], qa[g][kc], st[ct], 0, 0, 0);
            }
            // P = exp2(S^T) in-register: lane holds P[qrow=m16][key=ct*16+quad*4+r]
            // == x16-MFMA A-operand layout (row=m16, k=quad*4+e). PV + row-sum.
#pragma unroll
            for (int ct = 0; ct < 4; ++ct) {
                bf16x4 pe;
#pragma unroll
                for (int r = 0; r < 4; ++r)
                    pe[r] = (__bf16)__builtin_amdgcn_exp2f(st[ct][r]);
                o[g]  = mfma16(pe, vb16[ct], o[g]);
                o2[g] = mfma16(pe, ones,     o2[g]);
            }
        }
        __syncthreads();  // next buffer staged; current buffer reads done
    }

    // Guard for the inline-asm MFMA fallback (compiler-unknown latency).
    asm volatile("s_nop 7\n\ts_nop 7");

    if (nspl == 1) {
#pragma unroll
        for (int g = 0; g < 2; ++g) {
#pragma unroll
            for (int r = 0; r < 4; ++r) {
                const int n = qt * 256 + g * 128 + wave * 16 + quad * 4 + r;
                const float val = o[g][r] / o2[g][r];
                const size_t addr = (size_t)b * 2621440
                                  + (size_t)(hh * 512 + (n >> 3)) * 640 + 512 + (n & 7) * 16 + m16;
                if (bf) ((__bf16*)out)[addr] = (__bf16)val;
                else    ((float*)out)[addr]  = val;
            }
        }
    } else {
        // fp32 partials; lane (m16, quad) owns O[n=..+quad*4+r][c=m16].
#pragma unroll
        for (int g = 0; g < 2; ++g) {
#pragma unroll
            for (int r = 0; r < 4; ++r) {
                const int n = qt * 256 + g * 128 + wave * 16 + quad * 4 + r;
                const size_t rowi = ((size_t)spl * 16 + bh) * 4096 + n;
                po[rowi * 16 + m16] = o[g][r];
                if (m16 == 0) pl[rowi] = o2[g][r];  // replicated across cols
            }
        }
    }
}

// ---------------------------------------------------------------------------
// Combine split-K partials: out = (sum_spl po) / (sum_spl pl).
// One thread per (bh, n) row; writes 16 contiguous channels (vectorized).
// ---------------------------------------------------------------------------
__global__ __launch_bounds__(256) void flash_combine(const float* __restrict__ po,
                                                     const float* __restrict__ pl,
                                                     void* __restrict__ out,
                                                     const int* __restrict__ flag,
                                                     int nspl)
{
    const int bf = *flag;
    const int tid = blockIdx.x * 256 + threadIdx.x;  // 65536 rows
    const int bh = tid >> 12, n = tid & 4095;
    const int b = bh >> 3, hh = bh & 7;

    f32x4 acc[4];
#pragma unroll
    for (int q = 0; q < 4; ++q) acc[q] = (f32x4){0.f, 0.f, 0.f, 0.f};
    float l = 0.f;
    for (int sp = 0; sp < nspl; ++sp) {
        const size_t rowi = ((size_t)sp * 16 + bh) * 4096 + n;
        const f32x4* r = (const f32x4*)(po + rowi * 16);
#pragma unroll
        for (int q = 0; q < 4; ++q) {
            const f32x4 v = r[q];
#pragma unroll
            for (int e = 0; e < 4; ++e) acc[q][e] += v[e];
        }
        l += pl[rowi];
    }
    const float inv = 1.f / l;
    const size_t addr = (size_t)b * 2621440
                      + (size_t)(hh * 512 + (n >> 3)) * 640 + 512 + (n & 7) * 16;
    if (bf) {
#pragma unroll
        for (int q = 0; q < 2; ++q) {
            bf16x8 w;
#pragma unroll
            for (int e = 0; e < 8; ++e) w[e] = (__bf16)(acc[q * 2 + (e >> 2)][e & 3] * inv);
            *(bf16x8*)((__bf16*)out + addr + q * 8) = w;
        }
    } else {
#pragma unroll
        for (int q = 0; q < 4; ++q) {
            f32x4 w;
#pragma unroll
            for (int e = 0; e < 4; ++e) w[e] = acc[q][e] * inv;
            *(f32x4*)((float*)out + addr + q * 4) = w;
        }
    }
}

// ---------------------------------------------------------------------------
extern "C" void kernel_launch(void* const* d_in, const int* in_sizes, int n_in,
                              void* d_out, int out_size, void* d_ws, size_t ws_size,
                              hipStream_t stream)
{
    const void* s    = d_in[0];
    const void* h_   = d_in[1];
    const void* sh   = d_in[2];
    const void* t1   = d_in[3];
    const void* t2   = d_in[4];
    const void* Wq_c = d_in[5];
    const void* Wq_s = d_in[6];
    const void* Wk_c = d_in[7];
    const void* Wv_c = d_in[8];
    const void* Wk_s = d_in[9];
    const void* Wv_s = d_in[10];

    const dim3 blk(256);
    const size_t PROJ = 4194304;  // 8192*512 bf16 elements

    const size_t WIDE_BYTES = 5 * PROJ * 2 + 1048576 * 2 + 65536 * 4 + 65536 * 2 + 256;
    const size_t QK_BYTES = 512ull * 4096 * 4;  // 8 MB atomic-free qk partials

    if (ws_size >= WIDE_BYTES) {
        // ---------------- wide path (CONFIRMED LIVE, R19 counters) --------
        __bf16* qc = (__bf16*)d_ws;
        __bf16* kc = qc + PROJ;
        __bf16* vc = kc + PROJ;
        __bf16* qs = vc + PROJ;
        __bf16* ks = qs + PROJ;
        __bf16* vs = ks + PROJ;            // 8192x128 row-major
        float*  Sb = (float*)(vs + 1048576);
        __bf16* Pb = (__bf16*)(Sb + 65536);
        int*  flag = (int*)(Pb + 65536);

        detect_dtype<<<dim3(1), dim3(64), 0, stream>>>((const unsigned*)t1, flag);

        ProjArgs pa{};
        const void* Xs[6] = {s, sh, sh, sh, sh, h_};
        const void* Ws[6] = {Wq_c, Wk_c, Wv_c, Wq_s, Wk_s, Wv_s};
        __bf16*     Ys[6] = {qc, kc, vc, qs, ks, vs};
        const int   Ks_[6] = {512, 512, 512, 512, 512, 128};
        const int   yt[6] = {4, 4, 4, 4, 4, 1};  // 128-wide N tiles
        pa.ng = 6;
        int ofs = 0;
        for (int g = 0; g < 6; ++g) {
            pa.X[g] = Xs[g]; pa.W[g] = Ws[g]; pa.Y[g] = Ys[g]; pa.K[g] = Ks_[g];
            pa.yofs[g] = ofs; ofs += yt[g];
        }
        pa.yofs[6] = ofs;  // 21

        proj_gemm<<<dim3(64, 21), blk, 0, stream>>>(pa, flag);

        // Atomic-free qk chain if workspace has 8 MB beyond the wide layout
        // (scratch can't alias anything: chan_qk reads qc/kc, and qs/ks/vs/
        // vc/Sb/Pb are all still live at this point).
        if (ws_size >= WIDE_BYTES + QK_BYTES) {
            float* qkscr = (float*)((char*)d_ws + WIDE_BYTES);
            chan_qk<0><<<dim3(512), blk, 0, stream>>>(qc, kc, qkscr);
            chan_softmax<32><<<dim3(256), blk, 0, stream>>>(qkscr, t1, Pb, flag);
        } else {
            zero_f32<<<dim3(256), blk, 0, stream>>>(Sb, 65536);
            chan_qk<1><<<dim3(512), blk, 0, stream>>>(qc, kc, Sb);
            chan_softmax<1><<<dim3(256), blk, 0, stream>>>(Sb, t1, Pb, flag);
        }
        chan_av<<<dim3(1024), blk, 0, stream>>>(Pb, vc, d_out, flag);
        // split-K flash: partials live in dead qc/kc/vc region (25 MB,
        // consumed by chan_qk/chan_av which precede flash in-stream).
        float* po = (float*)qc;                  // 4*16*4096*16 f32 = 16.8 MB
        float* pl = po + 4ull * 1048576;         // 4*16*4096 f32
        flash_sa<0><<<dim3(256, 4), dim3(512), 0, stream>>>(qs, ks, vs, t2, d_out, po, pl, flag);
        flash_combine<<<dim3(256), blk, 0, stream>>>(po, pl, d_out, flag, 4);
    } else {
        // ---------------- fallback: sequential reuse (not the live path) --
        __bf16* A  = (__bf16*)d_ws;        // q_c -> v_c -> k_s
        __bf16* Bf = A + PROJ;             // k_c -> q_s
        __bf16* D  = Bf + PROJ;            // v_s: 8192x128 row-major
        float*  Sb = (float*)(D + 1048576);
        __bf16* Pb = (__bf16*)(Sb + 65536);
        int*  flag = (int*)(Pb + 65536);

        detect_dtype<<<dim3(1), dim3(64), 0, stream>>>((const unsigned*)t1, flag);

        auto mk2 = [&](const void* X0, const void* W0, __bf16* Y0, int K0, int t0,
                       const void* X1, const void* W1, __bf16* Y1, int K1, int t1_) {
            ProjArgs p{};
            p.ng = 2;
            p.X[0] = X0; p.W[0] = W0; p.Y[0] = Y0; p.K[0] = K0;
            p.X[1] = X1; p.W[1] = W1; p.Y[1] = Y1; p.K[1] = K1;
            p.yofs[0] = 0; p.yofs[1] = t0; p.yofs[2] = t0 + t1_;
            return p;
        };

        const size_t fb_end = (size_t)((char*)(flag + 1) - (char*)d_ws);
        const size_t pofs = (fb_end + 255) & ~(size_t)255;
        const size_t per_split = (1048576 + 65536) * 4;  // flash po + pl bytes/split
        int nspl = 1;
        if (ws_size >= pofs + 4 * per_split)      nspl = 4;
        else if (ws_size >= pofs + 2 * per_split) nspl = 2;
        const bool qk_part = (ws_size >= pofs + QK_BYTES);
        float* scratch = (float*)((char*)d_ws + pofs);

        ProjArgs p1 = mk2(s,  Wq_c, A,  512, 4, sh, Wk_c, Bf, 512, 4);
        proj_gemm<<<dim3(64, 8), blk, 0, stream>>>(p1, flag);
        if (qk_part) {
            chan_qk<0><<<dim3(512), blk, 0, stream>>>(A, Bf, scratch);
            chan_softmax<32><<<dim3(256), blk, 0, stream>>>(scratch, t1, Pb, flag);
        } else {
            zero_f32<<<dim3(256), blk, 0, stream>>>(Sb, 65536);
            chan_qk<1><<<dim3(512), blk, 0, stream>>>(A, Bf, Sb);
            chan_softmax<1><<<dim3(256), blk, 0, stream>>>(Sb, t1, Pb, flag);
        }

        ProjArgs p2 = mk2(sh, Wv_c, A, 512, 4, sh, Wq_s, Bf, 512, 4);
        proj_gemm<<<dim3(64, 8), blk, 0, stream>>>(p2, flag);
        chan_av<<<dim3(1024), blk, 0, stream>>>(Pb, A, d_out, flag);

        ProjArgs p3 = mk2(sh, Wk_s, A, 512, 4, h_, Wv_s, D, 128, 1);
        proj_gemm<<<dim3(64, 5), blk, 0, stream>>>(p3, flag);

        float* po = scratch;
        float* pl = po + (size_t)nspl * 1048576;
        flash_sa<1><<<dim3(256, nspl), dim3(512), 0, stream>>>(Bf, A, D, t2, d_out, po, pl, flag);
        if (nspl > 1)
            flash_combine<<<dim3(256), blk, 0, stream>>>(po, pl, d_out, flag, nspl);
    }
}

// Round 16
// 214.729 us; speedup vs baseline: 1.0251x; 1.0016x over previous
//
#include <hip/hip_runtime.h>

// WCSA: B=2, N=4096, Cc=C=512, Cs=128, H=8, dc=d=64, ds=16.
// Internal compute: bf16 MFMA + fp32 accumulation. I/O dtype runtime-detected
// (fp32 confirmed; bf16 path kept).
//
// Head layout: reshape(B,N,C)->(B,H,N,d) direct => head h of a projection is
// the contiguous 512-row slab, row-major (4096,d).
//
// R23:
//  (1) proj LDS double-buffer, ONE barrier per K-step (was 2). R19/R22
//      counters: proj latency-bound (MfmaUtil 12.5, occ 27.8, ~2.2
//      blocks/CU) -- barrier drains with nothing co-resident are the
//      stall. As/Bs[2] = 73.7KB (2 blocks/CU = current residency, no
//      loss); staging of tile k+1 overlaps MFMA on tile k; loop's final
//      barrier doubles as the epilogue-overlay guard.
//  (2) detect_dtype launch removed: flag = 2 ALU ops, computed inline in
//      each kernel from its temperature pointer ((w>>16)==(w&0xffff)).
//      7 launches -> 6.
// flash = control (~67-70us, noise +-3%).

typedef __attribute__((ext_vector_type(8))) __bf16 bf16x8;
typedef __attribute__((ext_vector_type(4))) __bf16 bf16x4;
typedef __attribute__((ext_vector_type(4))) float  f32x4;
typedef __attribute__((ext_vector_type(4))) short  s16x4;

#define LOG2E 1.44269504088896340736f

static __device__ __forceinline__ int is_bf16_io(const unsigned* p)
{
    const unsigned w = p[0];
    return (w >> 16) == (w & 0xffffu);
}

// 16x16x16 bf16 MFMA: A/B = 4 bf16 (2 VGPRs), C/D = 4 f32.
static __device__ __forceinline__ f32x4 mfma16(bf16x4 a, bf16x4 b, f32x4 c)
{
#if __has_builtin(__builtin_amdgcn_mfma_f32_16x16x16bf16_1k)
    union { bf16x4 h; s16x4 s; } ua, ub;
    ua.h = a; ub.h = b;
    return __builtin_amdgcn_mfma_f32_16x16x16bf16_1k(ua.s, ub.s, c, 0, 0, 0);
#elif __has_builtin(__builtin_amdgcn_mfma_f32_16x16x16_bf16)
    return __builtin_amdgcn_mfma_f32_16x16x16_bf16(a, b, c, 0, 0, 0);
#else
    asm("v_mfma_f32_16x16x16_bf16 %0, %1, %2, %0" : "+v"(c) : "v"(a), "v"(b));
    return c;
#endif
}

// ---------------------------------------------------------------------------
// Fused projection GEMMs, 128(M)x128(N) tile, BK=64, register prefetch,
// DOUBLE-BUFFERED LDS with one barrier per K-step.
// 4 waves in 2(M)x2(N); wave tile 64x64 = 4x4 of 16x16x32 MFMA (32 MFMA/iter).
// blockIdx.y -> group via prefix table in units of 128-wide N-tiles.
// Coalesced epilogue: acc -> wave-private LDS C[wave][64][72] (overlays
// the A-buffers) -> row-contiguous bf16x8 global stores (full 64B lines).
// LDS row stride 72 bf16.
// ---------------------------------------------------------------------------
struct ProjArgs {
    const void* X[6];
    const void* W[6];
    __bf16*     Y[6];
    int         K[6];
    int         yofs[7];  // units of 128-wide N tiles
    int         ng;
};

__global__ __launch_bounds__(256) void proj_gemm(ProjArgs args,
                                                 const unsigned* __restrict__ tw)
{
    __shared__ __align__(16) union ShMem {
        struct { __bf16 A[2][128][72]; __bf16 B[2][128][72]; } s;  // 73728 B
        __bf16 C[4][64][72];                                       // 36864 B
    } sm;

    const int bf = is_bf16_io(tw);
    const int by = blockIdx.y;
    int g = 0;
    while (by >= args.yofs[g + 1]) ++g;  // <=6 iters, wave-uniform
    const int n0 = (by - args.yofs[g]) * 128;
    const int N  = (args.yofs[g + 1] - args.yofs[g]) * 128;
    const int K  = args.K[g];
    const void* X = args.X[g];
    const void* W = args.W[g];
    __bf16*     Y = args.Y[g];

    const int m0 = blockIdx.x * 128;
    const int t = threadIdx.x;
    const int wave = t >> 6, lane = t & 63;
    const int wr = (wave >> 1) * 64, wc = (wave & 1) * 64;
    const int m16 = lane & 15, quad = lane >> 4;

    f32x4 acc[4][4];
#pragma unroll
    for (int i = 0; i < 4; ++i)
#pragma unroll
        for (int j = 0; j < 4; ++j) acc[i][j] = (f32x4){0.f, 0.f, 0.f, 0.f};

    if (bf) {
        // ---- bf16 inputs: prefetch A 4x + B 4x bf16x8 ----
        const __bf16* Xb = (const __bf16*)X;
        const __bf16* Wb = (const __bf16*)W;
        bf16x8 pa[4], pb[4];
        auto load = [&](int k0) {
#pragma unroll
            for (int i = 0; i < 4; ++i) {
                const int idx = t + i * 256, row = idx >> 3, off = (idx & 7) * 8;
                pa[i] = *(const bf16x8*)(Xb + (size_t)(m0 + row) * K + k0 + off);
            }
#pragma unroll
            for (int i = 0; i < 4; ++i) {
                const int idx = t + i * 256, row = idx >> 3, off = (idx & 7) * 8;
                pb[i] = *(const bf16x8*)(Wb + (size_t)(n0 + row) * K + k0 + off);
            }
        };
        auto store = [&](int bi) {
#pragma unroll
            for (int i = 0; i < 4; ++i) {
                const int idx = t + i * 256, row = idx >> 3, off = (idx & 7) * 8;
                *(bf16x8*)&sm.s.A[bi][row][off] = pa[i];
            }
#pragma unroll
            for (int i = 0; i < 4; ++i) {
                const int idx = t + i * 256, row = idx >> 3, off = (idx & 7) * 8;
                *(bf16x8*)&sm.s.B[bi][row][off] = pb[i];
            }
        };
        load(0);
        store(0);
        if (64 < K) load(64);
        __syncthreads();
        int step = 0;
        for (int k0 = 0; k0 < K; k0 += 64, ++step) {
            const int cur = step & 1;
            if (k0 + 64 < K)  store(cur ^ 1);
            if (k0 + 128 < K) load(k0 + 128);
#pragma unroll
            for (int kc = 0; kc < 2; ++kc) {
                const int ko = kc * 32 + quad * 8;
                bf16x8 a[4], b[4];
#pragma unroll
                for (int i = 0; i < 4; ++i) a[i] = *(const bf16x8*)&sm.s.A[cur][wr + i * 16 + m16][ko];
#pragma unroll
                for (int j = 0; j < 4; ++j) b[j] = *(const bf16x8*)&sm.s.B[cur][wc + j * 16 + m16][ko];
#pragma unroll
                for (int i = 0; i < 4; ++i)
#pragma unroll
                    for (int j = 0; j < 4; ++j)
                        acc[i][j] = __builtin_amdgcn_mfma_f32_16x16x32_bf16(a[i], b[j], acc[i][j], 0, 0, 0);
            }
            __syncthreads();
        }
    } else {
        // ---- fp32 inputs: prefetch A 8x + B 8x f32x4 (cvt at store) ----
        const float* Xf = (const float*)X;
        const float* Wf = (const float*)W;
        f32x4 pa[8], pb[8];
        auto load = [&](int k0) {
#pragma unroll
            for (int i = 0; i < 8; ++i) {
                const int idx = t + i * 256, row = idx >> 4, c = (idx & 15) * 4;
                pa[i] = *(const f32x4*)(Xf + (size_t)(m0 + row) * K + k0 + c);
            }
#pragma unroll
            for (int i = 0; i < 8; ++i) {
                const int idx = t + i * 256, row = idx >> 4, c = (idx & 15) * 4;
                pb[i] = *(const f32x4*)(Wf + (size_t)(n0 + row) * K + k0 + c);
            }
        };
        auto store = [&](int bi) {
#pragma unroll
            for (int i = 0; i < 8; ++i) {
                const int idx = t + i * 256, row = idx >> 4, c = (idx & 15) * 4;
                bf16x4 ha;
#pragma unroll
                for (int e = 0; e < 4; ++e) ha[e] = (__bf16)pa[i][e];
                *(bf16x4*)&sm.s.A[bi][row][c] = ha;
            }
#pragma unroll
            for (int i = 0; i < 8; ++i) {
                const int idx = t + i * 256, row = idx >> 4, c = (idx & 15) * 4;
                bf16x4 hb;
#pragma unroll
                for (int e = 0; e < 4; ++e) hb[e] = (__bf16)pb[i][e];
                *(bf16x4*)&sm.s.B[bi][row][c] = hb;
            }
        };
        load(0);
        store(0);
        if (64 < K) load(64);
        __syncthreads();
        int step = 0;
        for (int k0 = 0; k0 < K; k0 += 64, ++step) {
            const int cur = step & 1;
            if (k0 + 64 < K)  store(cur ^ 1);
            if (k0 + 128 < K) load(k0 + 128);
#pragma unroll
            for (int kc = 0; kc < 2; ++kc) {
                const int ko = kc * 32 + quad * 8;
                bf16x8 a[4], b[4];
#pragma unroll
                for (int i = 0; i < 4; ++i) a[i] = *(const bf16x8*)&sm.s.A[cur][wr + i * 16 + m16][ko];
#pragma unroll
                for (int j = 0; j < 4; ++j) b[j] = *(const bf16x8*)&sm.s.B[cur][wc + j * 16 + m16][ko];
#pragma unroll
                for (int i = 0; i < 4; ++i)
#pragma unroll
                    for (int j = 0; j < 4; ++j)
                        acc[i][j] = __builtin_amdgcn_mfma_f32_16x16x32_bf16(a[i], b[j], acc[i][j], 0, 0, 0);
            }
            __syncthreads();
        }
    }

    // ---- coalesced epilogue: acc -> LDS (wave-private) -> 128B stores ----
    // Loop's final barrier guarantees all frag reads done before C overlay.
#pragma unroll
    for (int i = 0; i < 4; ++i)
#pragma unroll
        for (int j = 0; j < 4; ++j)
#pragma unroll
            for (int r = 0; r < 4; ++r)
                sm.C[wave][i * 16 + quad * 4 + r][j * 16 + m16] = (__bf16)acc[i][j][r];
    // wave-private staging: in-wave LDS dependency, no barrier needed.
#pragma unroll
    for (int p = 0; p < 8; ++p) {
        const int row = p * 8 + (lane >> 3);
        const int c8  = (lane & 7) * 8;
        bf16x8 v = *(const bf16x8*)&sm.C[wave][row][c8];
        *(bf16x8*)&Y[(size_t)(m0 + wr + row) * N + n0 + wc + c8] = v;
    }
}

// ---------------------------------------------------------------------------
__global__ __launch_bounds__(256) void zero_f32(float* __restrict__ p, int n)
{
    const int i = blockIdx.x * 256 + threadIdx.x;
    if (i < n) p[i] = 0.f;
}

// ---------------------------------------------------------------------------
// Channel QK v3 (MFMA): S[bh][i][j] = sum_n Qc[n][i]*Kc[n][j], 32 n-splits
// of 128. Stage Q^T/K^T in LDS (coalesced loads + transpose scatter).
// ATOMIC=1: atomics into S (legacy). ATOMIC=0: plain stores into
// Spart[bx][64][64]; chan_softmax<32> consumes splits directly.
// ---------------------------------------------------------------------------
template <int ATOMIC>
__global__ __launch_bounds__(256) void chan_qk(const __bf16* __restrict__ Qc,
                                               const __bf16* __restrict__ Kc,
                                               float* __restrict__ S)
{
    __shared__ __align__(16) __bf16 Qt[64][136];  // [channel][token] (Q^T)
    __shared__ __align__(16) __bf16 Kt[64][136];
    const int bx = blockIdx.x;
    const int bh = bx >> 5, split = bx & 31;
    const int b = bh >> 3, hh = bh & 7;
    const int n0 = split * 128;
    const int t = threadIdx.x;
    const size_t base = ((size_t)b * 4096 + (size_t)hh * 512) * 512;

    for (int idx = t; idx < 1024; idx += 256) {
        const int row = idx >> 3, c0 = (idx & 7) * 8;  // token row, channel base
        bf16x8 q = *(const bf16x8*)(Qc + base + (size_t)(n0 + row) * 64 + c0);
        bf16x8 k = *(const bf16x8*)(Kc + base + (size_t)(n0 + row) * 64 + c0);
#pragma unroll
        for (int e = 0; e < 8; ++e) {
            Qt[c0 + e][row] = q[e];
            Kt[c0 + e][row] = k[e];
        }
    }
    __syncthreads();

    const int wave = t >> 6, lane = t & 63;
    const int m16 = lane & 15, quad = lane >> 4;

    f32x4 acc[4];
#pragma unroll
    for (int tj = 0; tj < 4; ++tj) acc[tj] = (f32x4){0.f, 0.f, 0.f, 0.f};

#pragma unroll
    for (int ks = 0; ks < 4; ++ks) {
        const int ko = ks * 32 + quad * 8;
        bf16x8 af = *(const bf16x8*)&Qt[wave * 16 + m16][ko];
#pragma unroll
        for (int tj = 0; tj < 4; ++tj) {
            bf16x8 bfr = *(const bf16x8*)&Kt[tj * 16 + m16][ko];
            acc[tj] = __builtin_amdgcn_mfma_f32_16x16x32_bf16(af, bfr, acc[tj], 0, 0, 0);
        }
    }

    if (ATOMIC) {
        float* Sb = S + (size_t)bh * 4096;
#pragma unroll
        for (int tj = 0; tj < 4; ++tj)
#pragma unroll
            for (int r = 0; r < 4; ++r)
                atomicAdd(&Sb[(wave * 16 + quad * 4 + r) * 64 + tj * 16 + m16], acc[tj][r]);
    } else {
        float* Sp = S + (size_t)bx * 4096;
#pragma unroll
        for (int tj = 0; tj < 4; ++tj)
#pragma unroll
            for (int r = 0; r < 4; ++r)
                Sp[(wave * 16 + quad * 4 + r) * 64 + tj * 16 + m16] = acc[tj][r];
    }
}

// ---------------------------------------------------------------------------
// Channel softmax v2: one WAVE per 64-elem row; shfl_xor max/sum.
// NSPLIT>1: fuses the qk split reduction (reads 32 partial tiles).
// Flag computed inline from temp.
// ---------------------------------------------------------------------------
template <int NSPLIT>
__global__ __launch_bounds__(256) void chan_softmax(const float* __restrict__ S,
                                                    const void* __restrict__ temp,
                                                    __bf16* __restrict__ P)
{
    const int bfio = is_bf16_io((const unsigned*)temp);
    const int row = blockIdx.x * 4 + (threadIdx.x >> 6);  // 0..1023
    const int bh = row >> 6, i = row & 63;
    const int hh = bh & 7;
    const int j = threadIdx.x & 63;
    const float tv = bfio ? (float)((const __bf16*)temp)[hh] : ((const float*)temp)[hh];
    const float scale = 0.125f * tv;

    float v;
    if (NSPLIT > 1) {
        const float* p = S + ((size_t)bh * NSPLIT) * 4096 + (size_t)i * 64 + j;
        float s = 0.f;
#pragma unroll
        for (int sp = 0; sp < NSPLIT; ++sp) s += p[(size_t)sp * 4096];
        v = s * scale;
    } else {
        v = S[(size_t)bh * 4096 + (size_t)i * 64 + j] * scale;
    }
    float mx = v;
#pragma unroll
    for (int d = 1; d < 64; d <<= 1) mx = fmaxf(mx, __shfl_xor(mx, d, 64));
    const float e = __builtin_amdgcn_exp2f((v - mx) * LOG2E);
    float sum = e;
#pragma unroll
    for (int d = 1; d < 64; d <<= 1) sum += __shfl_xor(sum, d, 64);
    P[(size_t)bh * 4096 + (size_t)i * 64 + j] = (__bf16)(e / sum);
}

// ---------------------------------------------------------------------------
// Channel AV v3 (MFMA + LDS-staged operands).
// out[b][h*512 + i*8 + n/512][n%512].
// ---------------------------------------------------------------------------
__global__ __launch_bounds__(256) void chan_av(const __bf16* __restrict__ P,
                                               const __bf16* __restrict__ Vc,
                                               void* __restrict__ out,
                                               const unsigned* __restrict__ tw)
{
    __shared__ __align__(16) __bf16 Pl[64][72];
    __shared__ __align__(16) __bf16 Vl[64][72];
    const int bf = is_bf16_io(tw);
    const int bx = blockIdx.x;
    const int bh = bx >> 6, ch = bx & 63;
    const int b = bh >> 3, hh = bh & 7;
    const int n0 = ch * 64;
    const int t = threadIdx.x, wave = t >> 6, lane = t & 63;
    const int m16 = lane & 15, quad = lane >> 4;
    const size_t base = ((size_t)b * 4096 + (size_t)hh * 512) * 512;  // Vc head slab
    const __bf16* Pb = P + (size_t)bh * 4096;

    {
        const int idx0 = t, row0 = idx0 >> 3, off0 = (idx0 & 7) * 8;
        const int idx1 = t + 256, row1 = idx1 >> 3, off1 = (idx1 & 7) * 8;
        *(bf16x8*)&Pl[row0][off0] = *(const bf16x8*)(Pb + (size_t)row0 * 64 + off0);
        *(bf16x8*)&Pl[row1][off1] = *(const bf16x8*)(Pb + (size_t)row1 * 64 + off1);
        *(bf16x8*)&Vl[row0][off0] = *(const bf16x8*)(Vc + base + (size_t)(n0 + row0) * 64 + off0);
        *(bf16x8*)&Vl[row1][off1] = *(const bf16x8*)(Vc + base + (size_t)(n0 + row1) * 64 + off1);
    }
    __syncthreads();

    bf16x8 a[2];
#pragma unroll
    for (int kc = 0; kc < 2; ++kc)
        a[kc] = *(const bf16x8*)&Pl[wave * 16 + m16][kc * 32 + quad * 8];

    f32x4 acc[4];
#pragma unroll
    for (int nt = 0; nt < 4; ++nt) {
        acc[nt] = (f32x4){0.f, 0.f, 0.f, 0.f};
        bf16x8 bv[2];
#pragma unroll
        for (int kc = 0; kc < 2; ++kc)
            bv[kc] = *(const bf16x8*)&Vl[nt * 16 + m16][kc * 32 + quad * 8];
#pragma unroll
        for (int kc = 0; kc < 2; ++kc)
            acc[nt] = __builtin_amdgcn_mfma_f32_16x16x32_bf16(a[kc], bv[kc], acc[nt], 0, 0, 0);
    }

#pragma unroll
    for (int nt = 0; nt < 4; ++nt) {
        const int n = n0 + nt * 16 + m16;
#pragma unroll
        for (int r = 0; r < 4; ++r) {
            const int i = wave * 16 + quad * 4 + r;
            const size_t addr = (size_t)b * 2621440
                              + (size_t)(hh * 512 + i * 8 + (n >> 9)) * 640 + (n & 511);
            if (bf) ((__bf16*)out)[addr] = (__bf16)acc[nt][r];
            else    ((float*)out)[addr]  = acc[nt][r];
        }
    }
}

// ---------------------------------------------------------------------------
// Spatial flash attention v8 (R13-proven form): 512-thread blocks, 8 waves x
// 2 q-groups = 256 q-rows/block; gridDim.y = nsplit key-splits (additive
// combine). Double-buffered K/V LDS (V transposed at stage), one barrier/iter.
// PV in-register via 16x16x16 MFMA; denominator via ones-B MFMA.
// Operand-swap S^T = mfma(K,Q); Q pre-scaled. Flag inline from temp2.
// Output: out[b][h*512 + n/8][512 + (n%8)*16 + c].
// ---------------------------------------------------------------------------
template <int PATH>
__global__ __launch_bounds__(512) void flash_sa(const __bf16* __restrict__ Qs,
                                                const __bf16* __restrict__ Ks,
                                                const __bf16* __restrict__ Vs,
                                                const void* __restrict__ temp2,
                                                void* __restrict__ out,
                                                float* __restrict__ po,
                                                float* __restrict__ pl)
{
    __shared__ __align__(16) __bf16 Kl[2][64][72];
    __shared__ __align__(16) __bf16 Vt[2][16][72];     // V^T: [c][key]
    const int bf = is_bf16_io((const unsigned*)temp2);
    const int bid = blockIdx.x;
    const int qt = bid & 15;            // 256-row q tile
    const int bh = bid >> 4;
    const int b = bh >> 3, hh = bh & 7;
    const int nspl = gridDim.y;
    const int spl  = blockIdx.y;
    const int nkt  = 64 / nspl;
    const int kt0  = spl * nkt;
    const int t = threadIdx.x, wave = t >> 6, lane = t & 63;
    const int m16 = lane & 15, quad = lane >> 4;
    const size_t base  = ((size_t)b * 4096 + (size_t)hh * 512) * 512;
    const size_t vbase = ((size_t)b * 4096 + (size_t)hh * 512) * 128;
    const float tv = bf ? (float)((const __bf16*)temp2)[hh] : ((const float*)temp2)[hh];
    const float sl = 0.125f * tv * LOG2E;

    // Q B-frags for 2 q-groups (lane m16 = qrow, k-contiguous), pre-scaled.
    bf16x8 qa[2][2];
#pragma unroll
    for (int g = 0; g < 2; ++g) {
        const int qrow = qt * 256 + g * 128 + wave * 16 + m16;
#pragma unroll
        for (int kc = 0; kc < 2; ++kc) {
            bf16x8 raw = *(const bf16x8*)(Qs + base + (size_t)qrow * 64 + kc * 32 + quad * 8);
#pragma unroll
            for (int e = 0; e < 8; ++e) qa[g][kc][e] = (__bf16)((float)raw[e] * sl);
        }
    }

    // Ones B-frag for denominator MFMA (row-sum of P).
    bf16x4 ones;
#pragma unroll
    for (int e = 0; e < 4; ++e) ones[e] = (__bf16)1.0f;

    // K/V prefetch registers. K: 512 chunks, 1 per thread. V: threads 0-255.
    const int krow = t >> 3, koff = (t & 7) * 8;
    const bool vact = t < 256;
    const int vrow = t & 63, vcq = (t >> 6) & 3;  // V: b64/thread, c = vcq*4..+4
    bf16x8 pk;
    bf16x4 pv;
    auto pref = [&](int kt) {
        pk = *(const bf16x8*)(Ks + base + (size_t)(kt * 64 + krow) * 64 + koff);
        if (vact) pv = *(const bf16x4*)(Vs + vbase + (size_t)(kt * 64 + vrow) * 16 + vcq * 4);
    };
    auto stage = [&](int bi) {
        *(bf16x8*)&Kl[bi][krow][koff] = pk;
        if (vact) {
#pragma unroll
            for (int e = 0; e < 4; ++e) Vt[bi][vcq * 4 + e][vrow] = pv[e];
        }
    };

    pref(kt0);
    stage(0);
    pref(kt0 + 1);
    __syncthreads();

    f32x4 o[2]  = {(f32x4){0.f, 0.f, 0.f, 0.f}, (f32x4){0.f, 0.f, 0.f, 0.f}};
    f32x4 o2[2] = {(f32x4){0.f, 0.f, 0.f, 0.f}, (f32x4){0.f, 0.f, 0.f, 0.f}};

    for (int kk = 0; kk < nkt; ++kk) {
        const int cur = kk & 1;

        // K/V fragments from current buffer (shared by both q-groups).
        bf16x8 kb[4][2];
        bf16x4 vb16[4];
#pragma unroll
        for (int ct = 0; ct < 4; ++ct)
#pragma unroll
            for (int kc = 0; kc < 2; ++kc)
                kb[ct][kc] = *(const bf16x8*)&Kl[cur][ct * 16 + m16][kc * 32 + quad * 8];
#pragma unroll
        for (int ct = 0; ct < 4; ++ct)
            vb16[ct] = *(const bf16x4*)&Vt[cur][m16][ct * 16 + quad * 4];

        // Stage tile kk+1 into the other buffer; prefetch tile kk+2.
        if (kk + 1 < nkt) stage(cur ^ 1);
        if (kk + 2 < nkt) pref(kt0 + kk + 2);

#pragma unroll
        for (int g = 0; g < 2; ++g) {
            // S^T tiles: D row = key-within-16 (quad*4+r), col = qrow (m16)
            f32x4 st[4];
#pragma unroll
            for (int ct = 0; ct < 4; ++ct) {
                st[ct] = (f32x4){0.f, 0.f, 0.f, 0.f};
#pragma unroll
                for (int kc = 0; kc < 2; ++kc)
                    st[ct] = __builtin_amdgcn_mfma_f32_16x16x32_bf16(kb[ct][kc], qa[g][kc], st[ct], 0, 0, 0);
            }
            // P = exp2(S^T) in-register: lane holds P[qrow=m16][key=ct*16+quad*4+r]
            // == x16-MFMA A-operand layout (row=m16, k=quad*4+e). PV + row-sum.
#pragma unroll
            for (int ct = 0; ct < 4; ++ct) {
                bf16x4 pe;
#pragma unroll
                for (int r = 0; r < 4; ++r)
                    pe[r] = (__bf16)__builtin_amdgcn_exp2f(st[ct][r]);
                o[g]  = mfma16(pe, vb16[ct], o[g]);
                o2[g] = mfma16(pe, ones,     o2[g]);
            }
        }
        __syncthreads();  // next buffer staged; current buffer reads done
    }

    // Guard for the inline-asm MFMA fallback (compiler-unknown latency).
    asm volatile("s_nop 7\n\ts_nop 7");

    if (nspl == 1) {
#pragma unroll
        for (int g = 0; g < 2; ++g) {
#pragma unroll
            for (int r = 0; r < 4; ++r) {
                const int n = qt * 256 + g * 128 + wave * 16 + quad * 4 + r;
                const float val = o[g][r] / o2[g][r];
                const size_t addr = (size_t)b * 2621440
                                  + (size_t)(hh * 512 + (n >> 3)) * 640 + 512 + (n & 7) * 16 + m16;
                if (bf) ((__bf16*)out)[addr] = (__bf16)val;
                else    ((float*)out)[addr]  = val;
            }
        }
    } else {
        // fp32 partials; lane (m16, quad) owns O[n=..+quad*4+r][c=m16].
#pragma unroll
        for (int g = 0; g < 2; ++g) {
#pragma unroll
            for (int r = 0; r < 4; ++r) {
                const int n = qt * 256 + g * 128 + wave * 16 + quad * 4 + r;
                const size_t rowi = ((size_t)spl * 16 + bh) * 4096 + n;
                po[rowi * 16 + m16] = o[g][r];
                if (m16 == 0) pl[rowi] = o2[g][r];  // replicated across cols
            }
        }
    }
}

// ---------------------------------------------------------------------------
// Combine split-K partials: out = (sum_spl po) / (sum_spl pl).
// One thread per (bh, n) row; writes 16 contiguous channels (vectorized).
// ---------------------------------------------------------------------------
__global__ __launch_bounds__(256) void flash_combine(const float* __restrict__ po,
                                                     const float* __restrict__ pl,
                                                     void* __restrict__ out,
                                                     const unsigned* __restrict__ tw,
                                                     int nspl)
{
    const int bf = is_bf16_io(tw);
    const int tid = blockIdx.x * 256 + threadIdx.x;  // 65536 rows
    const int bh = tid >> 12, n = tid & 4095;
    const int b = bh >> 3, hh = bh & 7;

    f32x4 acc[4];
#pragma unroll
    for (int q = 0; q < 4; ++q) acc[q] = (f32x4){0.f, 0.f, 0.f, 0.f};
    float l = 0.f;
    for (int sp = 0; sp < nspl; ++sp) {
        const size_t rowi = ((size_t)sp * 16 + bh) * 4096 + n;
        const f32x4* r = (const f32x4*)(po + rowi * 16);
#pragma unroll
        for (int q = 0; q < 4; ++q) {
            const f32x4 v = r[q];
#pragma unroll
            for (int e = 0; e < 4; ++e) acc[q][e] += v[e];
        }
        l += pl[rowi];
    }
    const float inv = 1.f / l;
    const size_t addr = (size_t)b * 2621440
                      + (size_t)(hh * 512 + (n >> 3)) * 640 + 512 + (n & 7) * 16;
    if (bf) {
#pragma unroll
        for (int q = 0; q < 2; ++q) {
            bf16x8 w;
#pragma unroll
            for (int e = 0; e < 8; ++e) w[e] = (__bf16)(acc[q * 2 + (e >> 2)][e & 3] * inv);
            *(bf16x8*)((__bf16*)out + addr + q * 8) = w;
        }
    } else {
#pragma unroll
        for (int q = 0; q < 4; ++q) {
            f32x4 w;
#pragma unroll
            for (int e = 0; e < 4; ++e) w[e] = acc[q][e] * inv;
            *(f32x4*)((float*)out + addr + q * 4) = w;
        }
    }
}

// ---------------------------------------------------------------------------
extern "C" void kernel_launch(void* const* d_in, const int* in_sizes, int n_in,
                              void* d_out, int out_size, void* d_ws, size_t ws_size,
                              hipStream_t stream)
{
    const void* s    = d_in[0];
    const void* h_   = d_in[1];
    const void* sh   = d_in[2];
    const void* t1   = d_in[3];
    const void* t2   = d_in[4];
    const void* Wq_c = d_in[5];
    const void* Wq_s = d_in[6];
    const void* Wk_c = d_in[7];
    const void* Wv_c = d_in[8];
    const void* Wk_s = d_in[9];
    const void* Wv_s = d_in[10];

    const unsigned* t1w = (const unsigned*)t1;
    const dim3 blk(256);
    const size_t PROJ = 4194304;  // 8192*512 bf16 elements

    const size_t WIDE_BYTES = 5 * PROJ * 2 + 1048576 * 2 + 65536 * 4 + 65536 * 2 + 256;
    const size_t QK_BYTES = 512ull * 4096 * 4;  // 8 MB atomic-free qk partials

    if (ws_size >= WIDE_BYTES) {
        // ---------------- wide path (CONFIRMED LIVE, R19 counters) --------
        __bf16* qc = (__bf16*)d_ws;
        __bf16* kc = qc + PROJ;
        __bf16* vc = kc + PROJ;
        __bf16* qs = vc + PROJ;
        __bf16* ks = qs + PROJ;
        __bf16* vs = ks + PROJ;            // 8192x128 row-major
        float*  Sb = (float*)(vs + 1048576);
        __bf16* Pb = (__bf16*)(Sb + 65536);

        ProjArgs pa{};
        const void* Xs[6] = {s, sh, sh, sh, sh, h_};
        const void* Ws[6] = {Wq_c, Wk_c, Wv_c, Wq_s, Wk_s, Wv_s};
        __bf16*     Ys[6] = {qc, kc, vc, qs, ks, vs};
        const int   Ks_[6] = {512, 512, 512, 512, 512, 128};
        const int   yt[6] = {4, 4, 4, 4, 4, 1};  // 128-wide N tiles
        pa.ng = 6;
        int ofs = 0;
        for (int g = 0; g < 6; ++g) {
            pa.X[g] = Xs[g]; pa.W[g] = Ws[g]; pa.Y[g] = Ys[g]; pa.K[g] = Ks_[g];
            pa.yofs[g] = ofs; ofs += yt[g];
        }
        pa.yofs[6] = ofs;  // 21

        proj_gemm<<<dim3(64, 21), blk, 0, stream>>>(pa, t1w);

        // Atomic-free qk chain if workspace has 8 MB beyond the wide layout.
        if (ws_size >= WIDE_BYTES + QK_BYTES) {
            float* qkscr = (float*)((char*)d_ws + WIDE_BYTES);
            chan_qk<0><<<dim3(512), blk, 0, stream>>>(qc, kc, qkscr);
            chan_softmax<32><<<dim3(256), blk, 0, stream>>>(qkscr, t1, Pb);
        } else {
            zero_f32<<<dim3(256), blk, 0, stream>>>(Sb, 65536);
            chan_qk<1><<<dim3(512), blk, 0, stream>>>(qc, kc, Sb);
            chan_softmax<1><<<dim3(256), blk, 0, stream>>>(Sb, t1, Pb);
        }
        chan_av<<<dim3(1024), blk, 0, stream>>>(Pb, vc, d_out, t1w);
        // split-K flash: partials live in dead qc/kc/vc region (25 MB,
        // consumed by chan_qk/chan_av which precede flash in-stream).
        float* po = (float*)qc;                  // 4*16*4096*16 f32 = 16.8 MB
        float* pl = po + 4ull * 1048576;         // 4*16*4096 f32
        flash_sa<0><<<dim3(256, 4), dim3(512), 0, stream>>>(qs, ks, vs, t2, d_out, po, pl);
        flash_combine<<<dim3(256), blk, 0, stream>>>(po, pl, d_out, t1w, 4);
    } else {
        // ---------------- fallback: sequential reuse (not the live path) --
        __bf16* A  = (__bf16*)d_ws;        // q_c -> v_c -> k_s
        __bf16* Bf = A + PROJ;             // k_c -> q_s
        __bf16* D  = Bf + PROJ;            // v_s: 8192x128 row-major
        float*  Sb = (float*)(D + 1048576);
        __bf16* Pb = (__bf16*)(Sb + 65536);
        int*  flag = (int*)(Pb + 65536);   // layout slot kept (unused)
        (void)flag;

        auto mk2 = [&](const void* X0, const void* W0, __bf16* Y0, int K0, int t0,
                       const void* X1, const void* W1, __bf16* Y1, int K1, int t1_) {
            ProjArgs p{};
            p.ng = 2;
            p.X[0] = X0; p.W[0] = W0; p.Y[0] = Y0; p.K[0] = K0;
            p.X[1] = X1; p.W[1] = W1; p.Y[1] = Y1; p.K[1] = K1;
            p.yofs[0] = 0; p.yofs[1] = t0; p.yofs[2] = t0 + t1_;
            return p;
        };

        const size_t fb_end = (size_t)((char*)(Pb + 65536) + 4 - (char*)d_ws);
        const size_t pofs = (fb_end + 255) & ~(size_t)255;
        const size_t per_split = (1048576 + 65536) * 4;  // flash po + pl bytes/split
        int nspl = 1;
        if (ws_size >= pofs + 4 * per_split)      nspl = 4;
        else if (ws_size >= pofs + 2 * per_split) nspl = 2;
        const bool qk_part = (ws_size >= pofs + QK_BYTES);
        float* scratch = (float*)((char*)d_ws + pofs);

        ProjArgs p1 = mk2(s,  Wq_c, A,  512, 4, sh, Wk_c, Bf, 512, 4);
        proj_gemm<<<dim3(64, 8), blk, 0, stream>>>(p1, t1w);
        if (qk_part) {
            chan_qk<0><<<dim3(512), blk, 0, stream>>>(A, Bf, scratch);
            chan_softmax<32><<<dim3(256), blk, 0, stream>>>(scratch, t1, Pb);
        } else {
            zero_f32<<<dim3(256), blk, 0, stream>>>(Sb, 65536);
            chan_qk<1><<<dim3(512), blk, 0, stream>>>(A, Bf, Sb);
            chan_softmax<1><<<dim3(256), blk, 0, stream>>>(Sb, t1, Pb);
        }

        ProjArgs p2 = mk2(sh, Wv_c, A, 512, 4, sh, Wq_s, Bf, 512, 4);
        proj_gemm<<<dim3(64, 8), blk, 0, stream>>>(p2, t1w);
        chan_av<<<dim3(1024), blk, 0, stream>>>(Pb, A, d_out, t1w);

        ProjArgs p3 = mk2(sh, Wk_s, A, 512, 4, h_, Wv_s, D, 128, 1);
        proj_gemm<<<dim3(64, 5), blk, 0, stream>>>(p3, t1w);

        float* po = scratch;
        float* pl = po + (size_t)nspl * 1048576;
        flash_sa<1><<<dim3(256, nspl), dim3(512), 0, stream>>>(Bf, A, D, t2, d_out, po, pl);
        if (nspl > 1)
            flash_combine<<<dim3(256), blk, 0, stream>>>(po, pl, d_out, t1w, nspl);
    }
}